// Round 2
// baseline (975.781 us; speedup 1.0000x reference)
//
#include <hip/hip_runtime.h>

// InvertedResidualQ on MI355X. Exact-integer quantized-conv formulation.
// ws footprint kept tiny (~12.9 MB): tables + xq codes. h3 staged in d_out.
// All convs on 4-bit codes are exact integer dots in f32 FMA (|d| < 2^24),
// so recomputation across kernels is bit-identical.

#define HW    12544      // 112*112
#define WID   112
#define CIN   32
#define CMID  192
#define COUT  32
#define NB    32
#define NPIX  (NB*HW)        // 401408
#define NX    (NB*CIN*HW)    // 12845056

// workspace layout (bytes); total need = 65536 + 12845056*... = ~12.91 MB
#define OFF_SCAL   0         // 4 u32 atomic-max slots: sx, s1, s2, s3
#define OFF_WSC    16        // 3 f32 weight scales
#define OFF_BN1    64        // gi[192], m[192], b[192]
#define OFF_BN2    2368
#define OFF_BN3    4672      // gi[32], m[32], b[32]
#define OFF_QW1    5120      // 192*32 f32 codes
#define OFF_QWDW   29696     // 192*9  f32 codes
#define OFF_QW2T   36608     // 192*32 f32 codes, [c][oc]
#define OFF_XQ     65536     // NPIX*32 i8, channel-last [pix][ic]

__device__ __forceinline__ float bmax256(float v, float* red) {
    const int t = threadIdx.x;
    red[t] = v; __syncthreads();
    for (int s = 128; s; s >>= 1) {
        if (t < s) red[t] = fmaxf(red[t], red[t + s]);
        __syncthreads();
    }
    float r = red[0]; __syncthreads();
    return r;
}

// round(clip(x/s, lo, 1) * n), half-even like jnp.round
__device__ __forceinline__ float qcode(float x, float s, float n, float lo) {
    float t = x / s;
    t = fminf(fmaxf(t, lo), 1.0f);
    return rintf(__fmul_rn(t, n));
}

// bn + relu6, identical instruction sequence wherever used (bit-exact recompute)
__device__ __forceinline__ float bnq(float d, float C, float m, float g, float b) {
    float y = __fmul_rn(d, C);
    float h = __fadd_rn(__fmul_rn(__fsub_rn(y, m), g), b);
    return fminf(fmaxf(h, 0.f), 6.f);
}

__device__ __forceinline__ void unpack32(const unsigned char* p, float* kx) {
    const uint4* q4 = (const uint4*)p;
    uint4 a = q4[0], b = q4[1];
    unsigned w[8] = {a.x, a.y, a.z, a.w, b.x, b.y, b.z, b.w};
#pragma unroll
    for (int j = 0; j < 8; ++j)
#pragma unroll
        for (int k = 0; k < 4; ++k)
            kx[4*j + k] = (float)((int)(w[j] << (24 - 8*k)) >> 24);
}

__global__ __launch_bounds__(256) void kprep(
    const float* __restrict__ w1, const float* __restrict__ wdw, const float* __restrict__ w2,
    const float* __restrict__ g1, const float* __restrict__ b1, const float* __restrict__ m1, const float* __restrict__ v1,
    const float* __restrict__ g2, const float* __restrict__ b2, const float* __restrict__ m2, const float* __restrict__ v2,
    const float* __restrict__ g3, const float* __restrict__ b3, const float* __restrict__ m3, const float* __restrict__ v3,
    unsigned char* __restrict__ ws)
{
    __shared__ float red[256];
    const int t = threadIdx.x;
    unsigned* scal = (unsigned*)(ws + OFF_SCAL);
    float* wsc  = (float*)(ws + OFF_WSC);
    float* bn1  = (float*)(ws + OFF_BN1);
    float* bn2  = (float*)(ws + OFF_BN2);
    float* bn3  = (float*)(ws + OFF_BN3);
    float* qw1  = (float*)(ws + OFF_QW1);
    float* qwdw = (float*)(ws + OFF_QWDW);
    float* qw2t = (float*)(ws + OFF_QW2T);

    if (t < 4) scal[t] = 0u;   // reset atomic-max slots (deterministic replay)

    float m;
    m = 0.f; for (int i = t; i < CMID*CIN; i += 256) m = fmaxf(m, fabsf(w1[i]));
    float sw1 = bmax256(m, red) + 1e-8f;
    m = 0.f; for (int i = t; i < CMID*9; i += 256) m = fmaxf(m, fabsf(wdw[i]));
    float swd = bmax256(m, red) + 1e-8f;
    m = 0.f; for (int i = t; i < COUT*CMID; i += 256) m = fmaxf(m, fabsf(w2[i]));
    float sw2 = bmax256(m, red) + 1e-8f;
    if (t == 0) { wsc[0] = sw1; wsc[1] = swd; wsc[2] = sw2; }

    for (int i = t; i < CMID*CIN; i += 256) qw1[i]  = qcode(w1[i],  sw1, 7.f, -1.f);
    for (int i = t; i < CMID*9;   i += 256) qwdw[i] = qcode(wdw[i], swd, 7.f, -1.f);
    for (int i = t; i < COUT*CMID; i += 256) {
        int oc = i / CMID, c = i % CMID;
        qw2t[c*COUT + oc] = qcode(w2[i], sw2, 7.f, -1.f);
    }

    for (int c = t; c < CMID; c += 256) {
        float vv1 = v1[c] + 1e-5f;
        bn1[c] = __fmul_rn(g1[c], (float)(1.0 / sqrt((double)vv1)));
        bn1[192+c] = m1[c]; bn1[384+c] = b1[c];
        float vv2 = v2[c] + 1e-5f;
        bn2[c] = __fmul_rn(g2[c], (float)(1.0 / sqrt((double)vv2)));
        bn2[192+c] = m2[c]; bn2[384+c] = b2[c];
    }
    for (int c = t; c < COUT; c += 256) {
        float vv3 = v3[c] + 1e-5f;
        bn3[c] = __fmul_rn(g3[c], (float)(1.0 / sqrt((double)vv3)));
        bn3[32+c] = m3[c]; bn3[64+c] = b3[c];
    }
}

__global__ __launch_bounds__(256) void kmaxx(const float4* __restrict__ x4,
                                             unsigned char* __restrict__ ws)
{
    __shared__ float red[256];
    float m = 0.f;
    for (size_t i = (size_t)blockIdx.x*256 + threadIdx.x; i < NX/4; i += (size_t)gridDim.x*256) {
        float4 v = x4[i];
        m = fmaxf(m, fmaxf(fmaxf(fabsf(v.x), fabsf(v.y)), fmaxf(fabsf(v.z), fabsf(v.w))));
    }
    float r = bmax256(m, red);
    if (threadIdx.x == 0) atomicMax((unsigned*)(ws + OFF_SCAL), __float_as_uint(r));
}

// quantize x -> xq codes (i8 channel-last), conv1 all 192 oc, reduce max(h1)
__global__ __launch_bounds__(256) void kmax1q(const float* __restrict__ x,
                                              unsigned char* __restrict__ ws)
{
    __shared__ float red[256];
    const int t = threadIdx.x;
    const unsigned* scal = (const unsigned*)(ws + OFF_SCAL);
    const float* wsc = (const float*)(ws + OFF_WSC);
    const float* bn1 = (const float*)(ws + OFF_BN1);
    const float* qw1 = (const float*)(ws + OFF_QW1);
    unsigned char* xq = ws + OFF_XQ;

    const float sx = __uint_as_float(scal[0]) + 1e-8f;
    const float C1 = (float)(((double)sx / 7.0) * ((double)wsc[0] / 7.0));

    const int p = blockIdx.x * 256 + t;
    const int n = p / HW, pi = p % HW;
    const float* xp = x + (size_t)n * CIN * HW + pi;

    float kx[CIN];
#pragma unroll
    for (int ic = 0; ic < CIN; ++ic) {
        float v = xp[(size_t)ic * HW] / sx;
        v = fminf(fmaxf(v, -1.f), 1.f);
        kx[ic] = rintf(__fmul_rn(v, 7.f));
    }

    unsigned wb[8];
#pragma unroll
    for (int j = 0; j < 8; ++j) {
        unsigned b0 = (unsigned)(int)kx[4*j]     & 0xffu;
        unsigned b1 = (unsigned)(int)kx[4*j + 1] & 0xffu;
        unsigned b2 = (unsigned)(int)kx[4*j + 2] & 0xffu;
        unsigned b3 = (unsigned)(int)kx[4*j + 3] & 0xffu;
        wb[j] = b0 | (b1 << 8) | (b2 << 16) | (b3 << 24);
    }
    uint4* q4 = (uint4*)(xq + (size_t)p * 32);
    q4[0] = make_uint4(wb[0], wb[1], wb[2], wb[3]);
    q4[1] = make_uint4(wb[4], wb[5], wb[6], wb[7]);

    float mx = 0.f;
    for (int oc = 0; oc < CMID; ++oc) {
        const float* wr = qw1 + oc * CIN;     // uniform -> scalar loads
        float d = 0.f;
#pragma unroll
        for (int ic = 0; ic < CIN; ++ic) d = fmaf(kx[ic], wr[ic], d);
        float h = bnq(d, C1, bn1[192+oc], bn1[oc], bn1[384+oc]);
        mx = fmaxf(mx, h);
    }
    float r = bmax256(mx, red);
    if (t == 0) atomicMax((unsigned*)(ws + OFF_SCAL) + 1, __float_as_uint(r));
}

// tile 14x14 out, halo 16x16 = 256 = blockDim: each thread owns one halo pos,
// keeps its 32 input codes in registers. Recompute conv1 -> j1 -> dw, max(h2).
__global__ __launch_bounds__(256) void kmax2(unsigned char* __restrict__ ws)
{
    __shared__ float jl[2][256];
    __shared__ float red[256];
    const int t = threadIdx.x;
    const unsigned* scal = (const unsigned*)(ws + OFF_SCAL);
    const float* wsc  = (const float*)(ws + OFF_WSC);
    const float* bn1  = (const float*)(ws + OFF_BN1);
    const float* bn2  = (const float*)(ws + OFF_BN2);
    const float* qw1  = (const float*)(ws + OFF_QW1);
    const float* qwdw = (const float*)(ws + OFF_QWDW);
    const unsigned char* xq = ws + OFF_XQ;

    const float sx  = __uint_as_float(scal[0]) + 1e-8f;
    const float s1v = __uint_as_float(scal[1]) + 1e-8f;
    const float C1  = (float)(((double)sx  / 7.0)  * ((double)wsc[0] / 7.0));
    const float C2  = (float)(((double)s1v / 15.0) * ((double)wsc[1] / 7.0));

    const int tile = blockIdx.x, n = blockIdx.y;
    const int ty = t >> 4, tx = t & 15;
    const int hy = (tile >> 3) * 14 - 1 + ty;
    const int wx = (tile & 7)  * 14 - 1 + tx;
    const bool inb = (hy >= 0 && hy < WID && wx >= 0 && wx < WID);
    const bool act = (ty < 14) && (tx < 14);

    float kx[CIN];
    if (inb) unpack32(xq + ((size_t)n * HW + hy * WID + wx) * 32, kx);
    else {
#pragma unroll
        for (int ic = 0; ic < CIN; ++ic) kx[ic] = 0.f;
    }

    float mx = 0.f;
    for (int c = 0; c < CMID; ++c) {
        const float* wr = qw1 + c * CIN;
        float d1 = 0.f;
#pragma unroll
        for (int ic = 0; ic < CIN; ++ic) d1 = fmaf(kx[ic], wr[ic], d1);
        float j1 = 0.f;
        if (inb) {
            float h1 = bnq(d1, C1, bn1[192+c], bn1[c], bn1[384+c]);
            j1 = rintf(__fmul_rn(fminf(h1 / s1v, 1.f), 15.f));
        }
        jl[c & 1][t] = j1;
        __syncthreads();
        if (act) {
            const float* wd = qwdw + c * 9;
            float d2 = 0.f;
#pragma unroll
            for (int dy = 0; dy < 3; ++dy)
#pragma unroll
                for (int dx = 0; dx < 3; ++dx)
                    d2 = fmaf(jl[c & 1][(ty+dy)*16 + tx+dx], wd[dy*3+dx], d2);
            float h2 = bnq(d2, C2, bn2[192+c], bn2[c], bn2[384+c]);
            mx = fmaxf(mx, h2);
        }
    }
    float r = bmax256(mx, red);
    if (t == 0) atomicMax((unsigned*)(ws + OFF_SCAL) + 2, __float_as_uint(r));
}

// same tiling; full chain conv1->j1->dw->j2->conv2->bn3; h3 -> d_out; max|h3|
__global__ __launch_bounds__(256) void kconv2(unsigned char* __restrict__ ws,
                                              float* __restrict__ h3)
{
    __shared__ float jl[2][256];
    __shared__ float red[256];
    const int t = threadIdx.x;
    const unsigned* scal = (const unsigned*)(ws + OFF_SCAL);
    const float* wsc  = (const float*)(ws + OFF_WSC);
    const float* bn1  = (const float*)(ws + OFF_BN1);
    const float* bn2  = (const float*)(ws + OFF_BN2);
    const float* bn3  = (const float*)(ws + OFF_BN3);
    const float* qw1  = (const float*)(ws + OFF_QW1);
    const float* qwdw = (const float*)(ws + OFF_QWDW);
    const float* qw2t = (const float*)(ws + OFF_QW2T);
    const unsigned char* xq = ws + OFF_XQ;

    const float sx  = __uint_as_float(scal[0]) + 1e-8f;
    const float s1v = __uint_as_float(scal[1]) + 1e-8f;
    const float s2v = __uint_as_float(scal[2]) + 1e-8f;
    const float C1  = (float)(((double)sx  / 7.0)  * ((double)wsc[0] / 7.0));
    const float C2  = (float)(((double)s1v / 15.0) * ((double)wsc[1] / 7.0));
    const float C3  = (float)(((double)s2v / 15.0) * ((double)wsc[2] / 7.0));

    const int tile = blockIdx.x, n = blockIdx.y;
    const int ty = t >> 4, tx = t & 15;
    const int hy = (tile >> 3) * 14 - 1 + ty;
    const int wx = (tile & 7)  * 14 - 1 + tx;
    const bool inb = (hy >= 0 && hy < WID && wx >= 0 && wx < WID);
    const bool act = (ty < 14) && (tx < 14);

    float kx[CIN];
    if (inb) unpack32(xq + ((size_t)n * HW + hy * WID + wx) * 32, kx);
    else {
#pragma unroll
        for (int ic = 0; ic < CIN; ++ic) kx[ic] = 0.f;
    }

    float acc[COUT];
#pragma unroll
    for (int oc = 0; oc < COUT; ++oc) acc[oc] = 0.f;

    for (int c = 0; c < CMID; ++c) {
        const float* wr = qw1 + c * CIN;
        float d1 = 0.f;
#pragma unroll
        for (int ic = 0; ic < CIN; ++ic) d1 = fmaf(kx[ic], wr[ic], d1);
        float j1 = 0.f;
        if (inb) {
            float h1 = bnq(d1, C1, bn1[192+c], bn1[c], bn1[384+c]);
            j1 = rintf(__fmul_rn(fminf(h1 / s1v, 1.f), 15.f));
        }
        jl[c & 1][t] = j1;
        __syncthreads();
        if (act) {
            const float* wd = qwdw + c * 9;
            float d2 = 0.f;
#pragma unroll
            for (int dy = 0; dy < 3; ++dy)
#pragma unroll
                for (int dx = 0; dx < 3; ++dx)
                    d2 = fmaf(jl[c & 1][(ty+dy)*16 + tx+dx], wd[dy*3+dx], d2);
            float h2 = bnq(d2, C2, bn2[192+c], bn2[c], bn2[384+c]);
            float j2 = rintf(__fmul_rn(fminf(h2 / s2v, 1.f), 15.f));
            const float* w2r = qw2t + c * COUT;
#pragma unroll
            for (int oc = 0; oc < COUT; ++oc) acc[oc] = fmaf(j2, w2r[oc], acc[oc]);
        }
    }

    float mx = 0.f;
    if (act) {
        const int gy = (tile >> 3) * 14 + ty;
        const int gx = (tile & 7)  * 14 + tx;
        const size_t base = (size_t)n * COUT * HW + gy * WID + gx;
#pragma unroll
        for (int oc = 0; oc < COUT; ++oc) {
            float y = __fmul_rn(acc[oc], C3);
            float h = __fadd_rn(__fmul_rn(__fsub_rn(y, bn3[32+oc]), bn3[oc]), bn3[64+oc]);
            h3[base + (size_t)oc * HW] = h;
            mx = fmaxf(mx, fabsf(h));
        }
    }
    float r = bmax256(mx, red);
    if (t == 0) atomicMax((unsigned*)(ws + OFF_SCAL) + 3, __float_as_uint(r));
}

// in-place on d_out: out = x + actq_signed(h3)
__global__ __launch_bounds__(256) void kout(const float4* __restrict__ x4,
                                            float4* __restrict__ io4,
                                            const unsigned char* __restrict__ ws)
{
    const unsigned* scal = (const unsigned*)(ws + OFF_SCAL);
    const float s3v = __uint_as_float(scal[3]) + 1e-8f;

    for (size_t i = (size_t)blockIdx.x*256 + threadIdx.x; i < NX/4; i += (size_t)gridDim.x*256) {
        float4 h = io4[i], xv = x4[i], o;
        float* hp = &h.x; float* xp = &xv.x; float* op = &o.x;
#pragma unroll
        for (int k = 0; k < 4; ++k) {
            float tq = fminf(fmaxf(hp[k] / s3v, -1.f), 1.f);
            float kq = rintf(__fmul_rn(tq, 7.f));
            float q  = __fmul_rn(kq / 7.f, s3v);
            op[k] = __fadd_rn(xp[k], q);
        }
        io4[i] = o;
    }
}

extern "C" void kernel_launch(void* const* d_in, const int* in_sizes, int n_in,
                              void* d_out, int out_size, void* d_ws, size_t ws_size,
                              hipStream_t stream)
{
    const float* x   = (const float*)d_in[0];
    const float* w1  = (const float*)d_in[1];
    const float* g1  = (const float*)d_in[2];
    const float* b1  = (const float*)d_in[3];
    const float* m1  = (const float*)d_in[4];
    const float* v1  = (const float*)d_in[5];
    const float* wdw = (const float*)d_in[6];
    const float* g2  = (const float*)d_in[7];
    const float* b2  = (const float*)d_in[8];
    const float* m2  = (const float*)d_in[9];
    const float* v2  = (const float*)d_in[10];
    const float* w2  = (const float*)d_in[11];
    const float* g3  = (const float*)d_in[12];
    const float* b3  = (const float*)d_in[13];
    const float* m3  = (const float*)d_in[14];
    const float* v3  = (const float*)d_in[15];
    unsigned char* ws = (unsigned char*)d_ws;

    hipLaunchKernelGGL(kprep, dim3(1), dim3(256), 0, stream,
                       w1, wdw, w2, g1, b1, m1, v1, g2, b2, m2, v2, g3, b3, m3, v3, ws);
    hipLaunchKernelGGL(kmaxx, dim3(2048), dim3(256), 0, stream, (const float4*)x, ws);
    hipLaunchKernelGGL(kmax1q, dim3(NPIX/256), dim3(256), 0, stream, x, ws);
    hipLaunchKernelGGL(kmax2, dim3(64, NB), dim3(256), 0, stream, ws);
    hipLaunchKernelGGL(kconv2, dim3(64, NB), dim3(256), 0, stream, ws, (float*)d_out);
    hipLaunchKernelGGL(kout, dim3(2048), dim3(256), 0, stream,
                       (const float4*)x, (float4*)d_out, ws);
}

// Round 3
// 738.684 us; speedup vs baseline: 1.3210x; 1.3210x over previous
//
#include <hip/hip_runtime.h>

// InvertedResidualQ on MI355X. Exact-integer quantized-conv formulation.
// ws ~12.9 MB: tables + xq codes. h3 staged in d_out. All convs on 4-bit codes
// are exact integer dots in f32 FMA (|d| < 2^24) -> cross-kernel recompute is
// bit-identical. R3: weights staged in LDS (was: global loads in hot loop,
// VALUBusy 24%); early-exit on clipped h1/h2 maxes (cap is 6.0 by construction).

#define HW    12544      // 112*112
#define WID   112
#define CIN   32
#define CMID  192
#define COUT  32
#define NB    32
#define NPIX  (NB*HW)        // 401408
#define NX    (NB*CIN*HW)    // 12845056

// workspace layout (bytes); total ~12.91 MB
#define OFF_SCAL   0         // 4 u32 atomic-max slots: sx, s1, s2, s3
#define OFF_WSC    16        // 3 f32 weight scales
#define OFF_BN1    64        // gi[192], m[192], b[192]
#define OFF_BN2    2368
#define OFF_BN3    4672      // gi[32], m[32], b[32]
#define OFF_QW1    5120      // 192*32 f32 codes
#define OFF_QWDW   29696     // 192*9  f32 codes
#define OFF_QW2T   36608     // 192*32 f32 codes, [c][oc]
#define OFF_XQ     65536     // NPIX*32 i8, channel-last [pix][ic]

__device__ __forceinline__ float bmax256(float v, float* red) {
    const int t = threadIdx.x;
    red[t] = v; __syncthreads();
    for (int s = 128; s; s >>= 1) {
        if (t < s) red[t] = fmaxf(red[t], red[t + s]);
        __syncthreads();
    }
    float r = red[0]; __syncthreads();
    return r;
}

// round(clip(x/s, lo, 1) * n), half-even like jnp.round
__device__ __forceinline__ float qcode(float x, float s, float n, float lo) {
    float t = x / s;
    t = fminf(fmaxf(t, lo), 1.0f);
    return rintf(__fmul_rn(t, n));
}

// bn + relu6, identical instruction sequence wherever used (bit-exact recompute)
__device__ __forceinline__ float bnq(float d, float C, float m, float g, float b) {
    float y = __fmul_rn(d, C);
    float h = __fadd_rn(__fmul_rn(__fsub_rn(y, m), g), b);
    return fminf(fmaxf(h, 0.f), 6.f);
}

__device__ __forceinline__ void unpack32(const unsigned char* p, float* kx) {
    const uint4* q4 = (const uint4*)p;
    uint4 a = q4[0], b = q4[1];
    unsigned w[8] = {a.x, a.y, a.z, a.w, b.x, b.y, b.z, b.w};
#pragma unroll
    for (int j = 0; j < 8; ++j)
#pragma unroll
        for (int k = 0; k < 4; ++k)
            kx[4*j + k] = (float)((int)(w[j] << (24 - 8*k)) >> 24);
}

__global__ __launch_bounds__(256) void kprep(
    const float* __restrict__ w1, const float* __restrict__ wdw, const float* __restrict__ w2,
    const float* __restrict__ g1, const float* __restrict__ b1, const float* __restrict__ m1, const float* __restrict__ v1,
    const float* __restrict__ g2, const float* __restrict__ b2, const float* __restrict__ m2, const float* __restrict__ v2,
    const float* __restrict__ g3, const float* __restrict__ b3, const float* __restrict__ m3, const float* __restrict__ v3,
    unsigned char* __restrict__ ws)
{
    __shared__ float red[256];
    const int t = threadIdx.x;
    unsigned* scal = (unsigned*)(ws + OFF_SCAL);
    float* wsc  = (float*)(ws + OFF_WSC);
    float* bn1  = (float*)(ws + OFF_BN1);
    float* bn2  = (float*)(ws + OFF_BN2);
    float* bn3  = (float*)(ws + OFF_BN3);
    float* qw1  = (float*)(ws + OFF_QW1);
    float* qwdw = (float*)(ws + OFF_QWDW);
    float* qw2t = (float*)(ws + OFF_QW2T);

    if (t < 4) scal[t] = 0u;   // reset atomic-max slots (deterministic replay)

    float m;
    m = 0.f; for (int i = t; i < CMID*CIN; i += 256) m = fmaxf(m, fabsf(w1[i]));
    float sw1 = bmax256(m, red) + 1e-8f;
    m = 0.f; for (int i = t; i < CMID*9; i += 256) m = fmaxf(m, fabsf(wdw[i]));
    float swd = bmax256(m, red) + 1e-8f;
    m = 0.f; for (int i = t; i < COUT*CMID; i += 256) m = fmaxf(m, fabsf(w2[i]));
    float sw2 = bmax256(m, red) + 1e-8f;
    if (t == 0) { wsc[0] = sw1; wsc[1] = swd; wsc[2] = sw2; }

    for (int i = t; i < CMID*CIN; i += 256) qw1[i]  = qcode(w1[i],  sw1, 7.f, -1.f);
    for (int i = t; i < CMID*9;   i += 256) qwdw[i] = qcode(wdw[i], swd, 7.f, -1.f);
    for (int i = t; i < COUT*CMID; i += 256) {
        int oc = i / CMID, c = i % CMID;
        qw2t[c*COUT + oc] = qcode(w2[i], sw2, 7.f, -1.f);
    }

    for (int c = t; c < CMID; c += 256) {
        float vv1 = v1[c] + 1e-5f;
        bn1[c] = __fmul_rn(g1[c], (float)(1.0 / sqrt((double)vv1)));
        bn1[192+c] = m1[c]; bn1[384+c] = b1[c];
        float vv2 = v2[c] + 1e-5f;
        bn2[c] = __fmul_rn(g2[c], (float)(1.0 / sqrt((double)vv2)));
        bn2[192+c] = m2[c]; bn2[384+c] = b2[c];
    }
    for (int c = t; c < COUT; c += 256) {
        float vv3 = v3[c] + 1e-5f;
        bn3[c] = __fmul_rn(g3[c], (float)(1.0 / sqrt((double)vv3)));
        bn3[32+c] = m3[c]; bn3[64+c] = b3[c];
    }
}

__global__ __launch_bounds__(256) void kmaxx(const float4* __restrict__ x4,
                                             unsigned char* __restrict__ ws)
{
    __shared__ float red[256];
    float m = 0.f;
    for (size_t i = (size_t)blockIdx.x*256 + threadIdx.x; i < NX/4; i += (size_t)gridDim.x*256) {
        float4 v = x4[i];
        m = fmaxf(m, fmaxf(fmaxf(fabsf(v.x), fabsf(v.y)), fmaxf(fabsf(v.z), fabsf(v.w))));
    }
    float r = bmax256(m, red);
    if (threadIdx.x == 0) atomicMax((unsigned*)(ws + OFF_SCAL), __float_as_uint(r));
}

// quantize x -> xq codes (i8 channel-last); conv1 max-scan with wave early-exit
// (h1 is clipped at 6 -> 6 is the provable cap of the max).
__global__ __launch_bounds__(256) void kmax1q(const float* __restrict__ x,
                                              unsigned char* __restrict__ ws)
{
    __shared__ __align__(16) float s_qw1[CMID*CIN];
    __shared__ float s_bn1[576];
    __shared__ float red[256];
    const int t = threadIdx.x;

    {   // stage tables in LDS (kills per-iteration global loads + aliasing stalls)
        const float4* src = (const float4*)(ws + OFF_QW1);
        float4* dst = (float4*)s_qw1;
        for (int i = t; i < CMID*CIN/4; i += 256) dst[i] = src[i];
        const float* b = (const float*)(ws + OFF_BN1);
        for (int i = t; i < 576; i += 256) s_bn1[i] = b[i];
    }

    const unsigned* scal = (const unsigned*)(ws + OFF_SCAL);
    const float* wsc = (const float*)(ws + OFF_WSC);
    unsigned char* xq = ws + OFF_XQ;

    const float sx = __uint_as_float(scal[0]) + 1e-8f;
    const float C1 = (float)(((double)sx / 7.0) * ((double)wsc[0] / 7.0));

    const int p = blockIdx.x * 256 + t;
    const int n = p / HW, pi = p % HW;
    const float* xp = x + (size_t)n * CIN * HW + pi;

    float kx[CIN];
#pragma unroll
    for (int ic = 0; ic < CIN; ++ic) {
        float v = xp[(size_t)ic * HW] / sx;
        v = fminf(fmaxf(v, -1.f), 1.f);
        kx[ic] = rintf(__fmul_rn(v, 7.f));
    }

    unsigned wb[8];
#pragma unroll
    for (int j = 0; j < 8; ++j) {
        unsigned b0 = (unsigned)(int)kx[4*j]     & 0xffu;
        unsigned b1 = (unsigned)(int)kx[4*j + 1] & 0xffu;
        unsigned b2 = (unsigned)(int)kx[4*j + 2] & 0xffu;
        unsigned b3 = (unsigned)(int)kx[4*j + 3] & 0xffu;
        wb[j] = b0 | (b1 << 8) | (b2 << 16) | (b3 << 24);
    }
    uint4* q4 = (uint4*)(xq + (size_t)p * 32);
    q4[0] = make_uint4(wb[0], wb[1], wb[2], wb[3]);
    q4[1] = make_uint4(wb[4], wb[5], wb[6], wb[7]);

    __syncthreads();   // LDS tables ready

    float mx = 0.f;
    for (int oc = 0; oc < CMID; ++oc) {
        const float* wr = s_qw1 + oc * CIN;
        float d = 0.f;
#pragma unroll
        for (int ic = 0; ic < CIN; ++ic) d = fmaf(kx[ic], wr[ic], d);
        float h = bnq(d, C1, s_bn1[192+oc], s_bn1[oc], s_bn1[384+oc]);
        mx = fmaxf(mx, h);
        if (__all(mx >= 6.0f)) break;    // wave-uniform break, no syncs in loop
    }
    float r = bmax256(mx, red);
    if (t == 0) atomicMax((unsigned*)(ws + OFF_SCAL) + 1, __float_as_uint(r));
}

// tile 14x14 out, halo 16x16 = 256 = blockDim. Recompute conv1 -> j1 -> dw,
// max(h2) with BLOCK-uniform early exit (h2 clipped at 6).
__global__ __launch_bounds__(256) void kmax2(unsigned char* __restrict__ ws)
{
    __shared__ __align__(16) float s_qw1[CMID*CIN];
    __shared__ __align__(16) float s_qwdw[CMID*9];
    __shared__ float s_bn1[576];
    __shared__ float s_bn2[576];
    __shared__ float jl[2][256];
    __shared__ float red[256];
    __shared__ unsigned doneflag;
    const int t = threadIdx.x;

    {
        const float4* s1p = (const float4*)(ws + OFF_QW1);
        float4* d1p = (float4*)s_qw1;
        for (int i = t; i < CMID*CIN/4; i += 256) d1p[i] = s1p[i];
        const float4* s2p = (const float4*)(ws + OFF_QWDW);
        float4* d2p = (float4*)s_qwdw;
        for (int i = t; i < CMID*9/4; i += 256) d2p[i] = s2p[i];
        const float* b1p = (const float*)(ws + OFF_BN1);
        const float* b2p = (const float*)(ws + OFF_BN2);
        for (int i = t; i < 576; i += 256) { s_bn1[i] = b1p[i]; s_bn2[i] = b2p[i]; }
        if (t == 0) doneflag = 0u;
    }

    const unsigned* scal = (const unsigned*)(ws + OFF_SCAL);
    const float* wsc = (const float*)(ws + OFF_WSC);
    const unsigned char* xq = ws + OFF_XQ;

    const float sx  = __uint_as_float(scal[0]) + 1e-8f;
    const float s1v = __uint_as_float(scal[1]) + 1e-8f;
    const float C1  = (float)(((double)sx  / 7.0)  * ((double)wsc[0] / 7.0));
    const float C2  = (float)(((double)s1v / 15.0) * ((double)wsc[1] / 7.0));

    const int tile = blockIdx.x, n = blockIdx.y;
    const int ty = t >> 4, tx = t & 15;
    const int hy = (tile >> 3) * 14 - 1 + ty;
    const int wx = (tile & 7)  * 14 - 1 + tx;
    const bool inb = (hy >= 0 && hy < WID && wx >= 0 && wx < WID);
    const bool act = (ty < 14) && (tx < 14);

    float kx[CIN];
    if (inb) unpack32(xq + ((size_t)n * HW + hy * WID + wx) * 32, kx);
    else {
#pragma unroll
        for (int ic = 0; ic < CIN; ++ic) kx[ic] = 0.f;
    }
    __syncthreads();   // LDS tables + doneflag ready

    float mx = 0.f;
    for (int c = 0; c < CMID; ++c) {
        const float* wr = s_qw1 + c * CIN;
        float d1 = 0.f;
#pragma unroll
        for (int ic = 0; ic < CIN; ++ic) d1 = fmaf(kx[ic], wr[ic], d1);
        float j1 = 0.f;
        if (inb) {
            float h1 = bnq(d1, C1, s_bn1[192+c], s_bn1[c], s_bn1[384+c]);
            j1 = rintf(__fmul_rn(fminf(h1 / s1v, 1.f), 15.f));
        }
        jl[c & 1][t] = j1;
        __syncthreads();
        if (act) {
            const float* wd = s_qwdw + c * 9;
            float d2 = 0.f;
#pragma unroll
            for (int dy = 0; dy < 3; ++dy)
#pragma unroll
                for (int dx = 0; dx < 3; ++dx)
                    d2 = fmaf(jl[c & 1][(ty+dy)*16 + tx+dx], wd[dy*3+dx], d2);
            float h2 = bnq(d2, C2, s_bn2[192+c], s_bn2[c], s_bn2[384+c]);
            mx = fmaxf(mx, h2);
        }
        if ((c & 7) == 7) {               // block-uniform early-exit check
            bool mine = act ? (mx >= 6.0f) : true;
            if (__all(mine) && (t & 63) == 0) atomicOr(&doneflag, 1u << (t >> 6));
            __syncthreads();
            if (doneflag == 0xFu) break;  // uniform across the block
        }
    }
    float r = bmax256(mx, red);
    if (t == 0) atomicMax((unsigned*)(ws + OFF_SCAL) + 2, __float_as_uint(r));
}

// same tiling; full chain conv1->j1->dw->j2->conv2->bn3; h3 -> d_out; max|h3|
__global__ __launch_bounds__(256) void kconv2(unsigned char* __restrict__ ws,
                                              float* __restrict__ h3)
{
    __shared__ __align__(16) float s_qw1[CMID*CIN];
    __shared__ __align__(16) float s_qwdw[CMID*9];
    __shared__ __align__(16) float s_qw2t[CMID*COUT];
    __shared__ float s_bn1[576];
    __shared__ float s_bn2[576];
    __shared__ float s_bn3[96];
    __shared__ float jl[2][256];
    __shared__ float red[256];
    const int t = threadIdx.x;

    {
        const float4* s1p = (const float4*)(ws + OFF_QW1);
        float4* d1p = (float4*)s_qw1;
        for (int i = t; i < CMID*CIN/4; i += 256) d1p[i] = s1p[i];
        const float4* s2p = (const float4*)(ws + OFF_QWDW);
        float4* d2p = (float4*)s_qwdw;
        for (int i = t; i < CMID*9/4; i += 256) d2p[i] = s2p[i];
        const float4* s3p = (const float4*)(ws + OFF_QW2T);
        float4* d3p = (float4*)s_qw2t;
        for (int i = t; i < CMID*COUT/4; i += 256) d3p[i] = s3p[i];
        const float* b1p = (const float*)(ws + OFF_BN1);
        const float* b2p = (const float*)(ws + OFF_BN2);
        const float* b3p = (const float*)(ws + OFF_BN3);
        for (int i = t; i < 576; i += 256) { s_bn1[i] = b1p[i]; s_bn2[i] = b2p[i]; }
        if (t < 96) s_bn3[t] = b3p[t];
    }

    const unsigned* scal = (const unsigned*)(ws + OFF_SCAL);
    const float* wsc = (const float*)(ws + OFF_WSC);
    const unsigned char* xq = ws + OFF_XQ;

    const float sx  = __uint_as_float(scal[0]) + 1e-8f;
    const float s1v = __uint_as_float(scal[1]) + 1e-8f;
    const float s2v = __uint_as_float(scal[2]) + 1e-8f;
    const float C1  = (float)(((double)sx  / 7.0)  * ((double)wsc[0] / 7.0));
    const float C2  = (float)(((double)s1v / 15.0) * ((double)wsc[1] / 7.0));
    const float C3  = (float)(((double)s2v / 15.0) * ((double)wsc[2] / 7.0));

    const int tile = blockIdx.x, n = blockIdx.y;
    const int ty = t >> 4, tx = t & 15;
    const int hy = (tile >> 3) * 14 - 1 + ty;
    const int wx = (tile & 7)  * 14 - 1 + tx;
    const bool inb = (hy >= 0 && hy < WID && wx >= 0 && wx < WID);
    const bool act = (ty < 14) && (tx < 14);

    float kx[CIN];
    if (inb) unpack32(xq + ((size_t)n * HW + hy * WID + wx) * 32, kx);
    else {
#pragma unroll
        for (int ic = 0; ic < CIN; ++ic) kx[ic] = 0.f;
    }
    __syncthreads();   // LDS tables ready

    float acc[COUT];
#pragma unroll
    for (int oc = 0; oc < COUT; ++oc) acc[oc] = 0.f;

    for (int c = 0; c < CMID; ++c) {
        const float* wr = s_qw1 + c * CIN;
        float d1 = 0.f;
#pragma unroll
        for (int ic = 0; ic < CIN; ++ic) d1 = fmaf(kx[ic], wr[ic], d1);
        float j1 = 0.f;
        if (inb) {
            float h1 = bnq(d1, C1, s_bn1[192+c], s_bn1[c], s_bn1[384+c]);
            j1 = rintf(__fmul_rn(fminf(h1 / s1v, 1.f), 15.f));
        }
        jl[c & 1][t] = j1;
        __syncthreads();
        if (act) {
            const float* wd = s_qwdw + c * 9;
            float d2 = 0.f;
#pragma unroll
            for (int dy = 0; dy < 3; ++dy)
#pragma unroll
                for (int dx = 0; dx < 3; ++dx)
                    d2 = fmaf(jl[c & 1][(ty+dy)*16 + tx+dx], wd[dy*3+dx], d2);
            float h2 = bnq(d2, C2, s_bn2[192+c], s_bn2[c], s_bn2[384+c]);
            float j2 = rintf(__fmul_rn(fminf(h2 / s2v, 1.f), 15.f));
            const float* w2r = s_qw2t + c * COUT;
#pragma unroll
            for (int oc = 0; oc < COUT; ++oc) acc[oc] = fmaf(j2, w2r[oc], acc[oc]);
        }
    }

    float mx = 0.f;
    if (act) {
        const int gy = (tile >> 3) * 14 + ty;
        const int gx = (tile & 7)  * 14 + tx;
        const size_t base = (size_t)n * COUT * HW + gy * WID + gx;
#pragma unroll
        for (int oc = 0; oc < COUT; ++oc) {
            float y = __fmul_rn(acc[oc], C3);
            float h = __fadd_rn(__fmul_rn(__fsub_rn(y, s_bn3[32+oc]), s_bn3[oc]), s_bn3[64+oc]);
            h3[base + (size_t)oc * HW] = h;
            mx = fmaxf(mx, fabsf(h));
        }
    }
    float r = bmax256(mx, red);
    if (t == 0) atomicMax((unsigned*)(ws + OFF_SCAL) + 3, __float_as_uint(r));
}

// in-place on d_out: out = x + actq_signed(h3)
__global__ __launch_bounds__(256) void kout(const float4* __restrict__ x4,
                                            float4* __restrict__ io4,
                                            const unsigned char* __restrict__ ws)
{
    const unsigned* scal = (const unsigned*)(ws + OFF_SCAL);
    const float s3v = __uint_as_float(scal[3]) + 1e-8f;

    for (size_t i = (size_t)blockIdx.x*256 + threadIdx.x; i < NX/4; i += (size_t)gridDim.x*256) {
        float4 h = io4[i], xv = x4[i], o;
        float* hp = &h.x; float* xp = &xv.x; float* op = &o.x;
#pragma unroll
        for (int k = 0; k < 4; ++k) {
            float tq = fminf(fmaxf(hp[k] / s3v, -1.f), 1.f);
            float kq = rintf(__fmul_rn(tq, 7.f));
            float q  = __fmul_rn(kq / 7.f, s3v);
            op[k] = __fadd_rn(xp[k], q);
        }
        io4[i] = o;
    }
}

extern "C" void kernel_launch(void* const* d_in, const int* in_sizes, int n_in,
                              void* d_out, int out_size, void* d_ws, size_t ws_size,
                              hipStream_t stream)
{
    const float* x   = (const float*)d_in[0];
    const float* w1  = (const float*)d_in[1];
    const float* g1  = (const float*)d_in[2];
    const float* b1  = (const float*)d_in[3];
    const float* m1  = (const float*)d_in[4];
    const float* v1  = (const float*)d_in[5];
    const float* wdw = (const float*)d_in[6];
    const float* g2  = (const float*)d_in[7];
    const float* b2  = (const float*)d_in[8];
    const float* m2  = (const float*)d_in[9];
    const float* v2  = (const float*)d_in[10];
    const float* w2  = (const float*)d_in[11];
    const float* g3  = (const float*)d_in[12];
    const float* b3  = (const float*)d_in[13];
    const float* m3  = (const float*)d_in[14];
    const float* v3  = (const float*)d_in[15];
    unsigned char* ws = (unsigned char*)d_ws;

    hipLaunchKernelGGL(kprep, dim3(1), dim3(256), 0, stream,
                       w1, wdw, w2, g1, b1, m1, v1, g2, b2, m2, v2, g3, b3, m3, v3, ws);
    hipLaunchKernelGGL(kmaxx, dim3(2048), dim3(256), 0, stream, (const float4*)x, ws);
    hipLaunchKernelGGL(kmax1q, dim3(NPIX/256), dim3(256), 0, stream, x, ws);
    hipLaunchKernelGGL(kmax2, dim3(64, NB), dim3(256), 0, stream, ws);
    hipLaunchKernelGGL(kconv2, dim3(64, NB), dim3(256), 0, stream, ws, (float*)d_out);
    hipLaunchKernelGGL(kout, dim3(2048), dim3(256), 0, stream,
                       (const float4*)x, (float4*)d_out, ws);
}

// Round 4
// 443.958 us; speedup vs baseline: 2.1979x; 1.6639x over previous
//
#include <hip/hip_runtime.h>

// InvertedResidualQ on MI355X. Exact-integer quantized-conv formulation.
// R4: sdot4 (v_dot4_i32_i8) for conv1/conv2 on packed i8 codes; division-free
// per-channel affine quantization j=rint(clamp(d*A+B,0,15)) EXHAUSTIVELY
// verified bit-exact per channel in kcoef (integer domain is finite), with
// exact-IEEE fallback per channel if verification fails. LDS cut to ~27KB.

#define HW    12544      // 112*112
#define WID   112
#define CIN   32
#define CMID  192
#define COUT  32
#define NB    32
#define NPIX  (NB*HW)        // 401408
#define NX    (NB*CIN*HW)    // 12845056

// workspace layout (bytes); ~12.3 MB total
#define OFF_SCAL   0         // 4 u32 atomic-max slots: sx, s1, s2, s3
#define OFF_WSC    16        // 3 f32 weight scales
#define OFF_BN1    64        // gi[192], m[192], b[192]
#define OFF_BN2    2368
#define OFF_BN3    4672      // gi[32], m[32], b[32]
#define OFF_W1P    5120      // 192*8 u32 packed i8 conv1 weights
#define OFF_WDW    11264     // 192*9 f32 dw codes
#define OFF_W2P    18176     // 48*32 u32 packed i8 conv2 weights [cgroup][oc]
#define OFF_FQ1    24320     // A[192] f32, B[192] f32, flag[192] u32
#define OFF_FQ2    26624     // same for stage 2
#define OFF_XQ     65536     // NPIX*32 i8 packed input codes, [pix][ic]

#if defined(__has_builtin)
#if __has_builtin(__builtin_amdgcn_sdot4)
#define HAVE_SDOT4 1
#endif
#endif

__device__ __forceinline__ int sdot4(unsigned a, unsigned b, int c) {
#ifdef HAVE_SDOT4
    return __builtin_amdgcn_sdot4((int)a, (int)b, c, false);
#else
    c += (int)(signed char)(a & 0xff)        * (int)(signed char)(b & 0xff);
    c += (int)(signed char)((a >> 8) & 0xff) * (int)(signed char)((b >> 8) & 0xff);
    c += (int)(signed char)((a >> 16) & 0xff)* (int)(signed char)((b >> 16) & 0xff);
    c += (int)(signed char)(a >> 24)         * (int)(signed char)(b >> 24);
    return c;
#endif
}

__device__ __forceinline__ float bmax256(float v, float* red) {
    const int t = threadIdx.x;
    red[t] = v; __syncthreads();
    for (int s = 128; s; s >>= 1) {
        if (t < s) red[t] = fmaxf(red[t], red[t + s]);
        __syncthreads();
    }
    float r = red[0]; __syncthreads();
    return r;
}

// round(clip(x/s, lo, 1) * n), half-even like jnp.round
__device__ __forceinline__ float qcode(float x, float s, float n, float lo) {
    float t = x / s;
    t = fminf(fmaxf(t, lo), 1.0f);
    return rintf(__fmul_rn(t, n));
}

// bn + relu6, identical instruction sequence wherever used (bit-exact recompute)
__device__ __forceinline__ float bnq(float d, float C, float m, float g, float b) {
    float y = __fmul_rn(d, C);
    float h = __fadd_rn(__fmul_rn(__fsub_rn(y, m), g), b);
    return fminf(fmaxf(h, 0.f), 6.f);
}

// exact quantization of (already relu6'd) h against scale s: rint(min(h/s,1)*15)
__device__ __forceinline__ float qexact15(float h, float s) {
    return rintf(__fmul_rn(fminf(h / s, 1.f), 15.f));
}
// fast affine quantization (verified per channel in kcoef)
__device__ __forceinline__ float qfast15(float df, float A, float B) {
    float t = fmaf(df, A, B);
    return rintf(fminf(fmaxf(t, 0.f), 15.f));
}

__global__ __launch_bounds__(256) void kprep(
    const float* __restrict__ w1, const float* __restrict__ wdw, const float* __restrict__ w2,
    const float* __restrict__ g1, const float* __restrict__ b1, const float* __restrict__ m1, const float* __restrict__ v1,
    const float* __restrict__ g2, const float* __restrict__ b2, const float* __restrict__ m2, const float* __restrict__ v2,
    const float* __restrict__ g3, const float* __restrict__ b3, const float* __restrict__ m3, const float* __restrict__ v3,
    unsigned char* __restrict__ ws)
{
    __shared__ float red[256];
    const int t = threadIdx.x;
    unsigned* scal = (unsigned*)(ws + OFF_SCAL);
    float* wsc  = (float*)(ws + OFF_WSC);
    float* bn1  = (float*)(ws + OFF_BN1);
    float* bn2  = (float*)(ws + OFF_BN2);
    float* bn3  = (float*)(ws + OFF_BN3);
    unsigned* w1p = (unsigned*)(ws + OFF_W1P);
    float*  wdwf  = (float*)(ws + OFF_WDW);
    unsigned* w2p = (unsigned*)(ws + OFF_W2P);

    if (t < 4) scal[t] = 0u;   // reset atomic-max slots (deterministic replay)

    float m;
    m = 0.f; for (int i = t; i < CMID*CIN; i += 256) m = fmaxf(m, fabsf(w1[i]));
    float sw1 = bmax256(m, red) + 1e-8f;
    m = 0.f; for (int i = t; i < CMID*9; i += 256) m = fmaxf(m, fabsf(wdw[i]));
    float swd = bmax256(m, red) + 1e-8f;
    m = 0.f; for (int i = t; i < COUT*CMID; i += 256) m = fmaxf(m, fabsf(w2[i]));
    float sw2 = bmax256(m, red) + 1e-8f;
    if (t == 0) { wsc[0] = sw1; wsc[1] = swd; wsc[2] = sw2; }

    // packed i8 conv1 weights: word (oc,j) holds ic = 4j..4j+3
    for (int i = t; i < CMID*8; i += 256) {
        int oc = i >> 3, j = i & 7;
        unsigned wword = 0;
#pragma unroll
        for (int k = 0; k < 4; ++k) {
            int code = (int)qcode(w1[oc*CIN + 4*j + k], sw1, 7.f, -1.f);
            wword |= ((unsigned)code & 0xffu) << (8*k);
        }
        w1p[i] = wword;
    }
    for (int i = t; i < CMID*9; i += 256) wdwf[i] = qcode(wdw[i], swd, 7.f, -1.f);
    // packed i8 conv2 weights: word (cg,oc) byte k = channel 4cg+k of output oc
    for (int i = t; i < 48*COUT; i += 256) {
        int cg = i >> 5, oc = i & 31;
        unsigned wword = 0;
#pragma unroll
        for (int k = 0; k < 4; ++k) {
            int code = (int)qcode(w2[oc*CMID + 4*cg + k], sw2, 7.f, -1.f);
            wword |= ((unsigned)code & 0xffu) << (8*k);
        }
        w2p[i] = wword;
    }

    for (int c = t; c < CMID; c += 256) {
        float vv1 = v1[c] + 1e-5f;
        bn1[c] = __fmul_rn(g1[c], (float)(1.0 / sqrt((double)vv1)));
        bn1[192+c] = m1[c]; bn1[384+c] = b1[c];
        float vv2 = v2[c] + 1e-5f;
        bn2[c] = __fmul_rn(g2[c], (float)(1.0 / sqrt((double)vv2)));
        bn2[192+c] = m2[c]; bn2[384+c] = b2[c];
    }
    for (int c = t; c < COUT; c += 256) {
        float vv3 = v3[c] + 1e-5f;
        bn3[c] = __fmul_rn(g3[c], (float)(1.0 / sqrt((double)vv3)));
        bn3[32+c] = m3[c]; bn3[64+c] = b3[c];
    }
}

__global__ __launch_bounds__(256) void kmaxx(const float4* __restrict__ x4,
                                             unsigned char* __restrict__ ws)
{
    __shared__ float red[256];
    float m = 0.f;
    for (size_t i = (size_t)blockIdx.x*256 + threadIdx.x; i < NX/4; i += (size_t)gridDim.x*256) {
        float4 v = x4[i];
        m = fmaxf(m, fmaxf(fmaxf(fabsf(v.x), fabsf(v.y)), fmaxf(fabsf(v.z), fabsf(v.w))));
    }
    float r = bmax256(m, red);
    if (threadIdx.x == 0) atomicMax((unsigned*)(ws + OFF_SCAL), __float_as_uint(r));
}

// quantize x -> xq packed codes; conv1 max-scan (sdot4) with wave early-exit
__global__ __launch_bounds__(256) void kmax1q(const float* __restrict__ x,
                                              unsigned char* __restrict__ ws)
{
    __shared__ unsigned s_w1p[CMID*8];
    __shared__ float s_bn1[576];
    __shared__ float red[256];
    const int t = threadIdx.x;

    {
        const uint4* src = (const uint4*)(ws + OFF_W1P);
        uint4* dst = (uint4*)s_w1p;
        for (int i = t; i < CMID*8/4; i += 256) dst[i] = src[i];
        const float* b = (const float*)(ws + OFF_BN1);
        for (int i = t; i < 576; i += 256) s_bn1[i] = b[i];
    }

    const unsigned* scal = (const unsigned*)(ws + OFF_SCAL);
    const float* wsc = (const float*)(ws + OFF_WSC);
    unsigned char* xq = ws + OFF_XQ;

    const float sx = __uint_as_float(scal[0]) + 1e-8f;
    const float C1 = (float)(((double)sx / 7.0) * ((double)wsc[0] / 7.0));

    const int p = blockIdx.x * 256 + t;
    const int n = p / HW, pi = p % HW;
    const float* xp = x + (size_t)n * CIN * HW + pi;

    float kx[CIN];
#pragma unroll
    for (int ic = 0; ic < CIN; ++ic) {
        float v = xp[(size_t)ic * HW] / sx;
        v = fminf(fmaxf(v, -1.f), 1.f);
        kx[ic] = rintf(__fmul_rn(v, 7.f));
    }

    unsigned wb[8];
#pragma unroll
    for (int j = 0; j < 8; ++j) {
        unsigned b0 = (unsigned)(int)kx[4*j]     & 0xffu;
        unsigned b1 = (unsigned)(int)kx[4*j + 1] & 0xffu;
        unsigned b2 = (unsigned)(int)kx[4*j + 2] & 0xffu;
        unsigned b3 = (unsigned)(int)kx[4*j + 3] & 0xffu;
        wb[j] = b0 | (b1 << 8) | (b2 << 16) | (b3 << 24);
    }
    uint4* q4 = (uint4*)(xq + (size_t)p * 32);
    q4[0] = make_uint4(wb[0], wb[1], wb[2], wb[3]);
    q4[1] = make_uint4(wb[4], wb[5], wb[6], wb[7]);

    __syncthreads();   // LDS tables ready

    float mx = 0.f;
    for (int oc = 0; oc < CMID; ++oc) {
        int d = 0;
#pragma unroll
        for (int j = 0; j < 8; ++j) d = sdot4(wb[j], s_w1p[oc*8 + j], d);
        float h = bnq((float)d, C1, s_bn1[192+oc], s_bn1[oc], s_bn1[384+oc]);
        mx = fmaxf(mx, h);
        if (__all(mx >= 6.0f)) break;    // 6 is the provable cap (relu6)
    }
    float r = bmax256(mx, red);
    if (t == 0) atomicMax((unsigned*)(ws + OFF_SCAL) + 1, __float_as_uint(r));
}

// per-channel fast-quant coefficients + EXHAUSTIVE bit-exactness verification
// over the full integer dot domain. stage 1: j1(d1), stage 2: j2(d2).
__global__ __launch_bounds__(64) void kcoef(unsigned char* __restrict__ ws, int stage)
{
    const unsigned* scal = (const unsigned*)(ws + OFF_SCAL);
    const float* wsc = (const float*)(ws + OFF_WSC);
    const int c = blockIdx.x, lane = threadIdx.x;
    const float* bn = (const float*)(ws + (stage == 1 ? OFF_BN1 : OFF_BN2));
    float* fq = (float*)(ws + (stage == 1 ? OFF_FQ1 : OFF_FQ2));

    float C, s; int R;
    if (stage == 1) {
        float sx = __uint_as_float(scal[0]) + 1e-8f;
        C = (float)(((double)sx / 7.0) * ((double)wsc[0] / 7.0));
        s = __uint_as_float(scal[1]) + 1e-8f;
        R = 1568;                          // |d1| <= 32*7*7
    } else {
        float s1 = __uint_as_float(scal[1]) + 1e-8f;
        C = (float)(((double)s1 / 15.0) * ((double)wsc[1] / 7.0));
        s = __uint_as_float(scal[2]) + 1e-8f;
        R = 945;                           // |d2| <= 9*15*7
    }
    const float gi = bn[c], mm = bn[192+c], bb = bn[384+c];
    const float A = (float)((double)C * (double)gi * 15.0 / (double)s);
    const float B = (float)(((double)bb - (double)mm * (double)gi) * 15.0 / (double)s);

    bool bad = false;
    for (int d = -R + lane; d <= R; d += 64) {
        float df = (float)d;
        float je = qexact15(bnq(df, C, mm, gi, bb), s);
        float jf = qfast15(df, A, B);
        if (je != jf) bad = true;
    }
    bool any = __any(bad);
    if (lane == 0) {
        fq[c] = A; fq[192+c] = B;
        ((unsigned*)fq)[384+c] = any ? 0u : 1u;   // 1 = fast path verified
    }
}

// tile 14x14 out, halo 16x16 = 256 = blockDim. conv1(sdot4) -> j1(fast) -> dw,
// max(h2) with block-uniform early exit (cap 6).
__global__ __launch_bounds__(256) void kmax2(unsigned char* __restrict__ ws)
{
    __shared__ unsigned s_w1p[CMID*8];
    __shared__ float s_wdw[CMID*9];
    __shared__ float s_bn2[576];
    __shared__ unsigned s_fq1[576];        // A,B (f32 bits), flag
    __shared__ float jl[2][256];
    __shared__ float red[256];
    __shared__ unsigned doneflag;
    const int t = threadIdx.x;

    {
        const uint4* sp = (const uint4*)(ws + OFF_W1P);
        uint4* dp = (uint4*)s_w1p;
        for (int i = t; i < CMID*8/4; i += 256) dp[i] = sp[i];
        const float* wp = (const float*)(ws + OFF_WDW);
        for (int i = t; i < CMID*9; i += 256) s_wdw[i] = wp[i];
        const float* b2p = (const float*)(ws + OFF_BN2);
        for (int i = t; i < 576; i += 256) s_bn2[i] = b2p[i];
        const unsigned* fp = (const unsigned*)(ws + OFF_FQ1);
        for (int i = t; i < 576; i += 256) s_fq1[i] = fp[i];
        if (t == 0) doneflag = 0u;
    }

    const unsigned* scal = (const unsigned*)(ws + OFF_SCAL);
    const float* wsc = (const float*)(ws + OFF_WSC);
    const float* gbn1 = (const float*)(ws + OFF_BN1);
    const unsigned char* xq = ws + OFF_XQ;

    const float sx  = __uint_as_float(scal[0]) + 1e-8f;
    const float s1v = __uint_as_float(scal[1]) + 1e-8f;
    const float C1  = (float)(((double)sx  / 7.0)  * ((double)wsc[0] / 7.0));
    const float C2  = (float)(((double)s1v / 15.0) * ((double)wsc[1] / 7.0));

    const int tile = blockIdx.x, n = blockIdx.y;
    const int ty = t >> 4, tx = t & 15;
    const int hy = (tile >> 3) * 14 - 1 + ty;
    const int wx = (tile & 7)  * 14 - 1 + tx;
    const bool inb = (hy >= 0 && hy < WID && wx >= 0 && wx < WID);
    const bool act = (ty < 14) && (tx < 14);

    unsigned wb[8];
    if (inb) {
        const uint4* q4 = (const uint4*)(xq + ((size_t)n * HW + hy * WID + wx) * 32);
        uint4 a = q4[0], b4 = q4[1];
        wb[0]=a.x; wb[1]=a.y; wb[2]=a.z; wb[3]=a.w;
        wb[4]=b4.x; wb[5]=b4.y; wb[6]=b4.z; wb[7]=b4.w;
    } else {
#pragma unroll
        for (int j = 0; j < 8; ++j) wb[j] = 0u;
    }
    __syncthreads();   // LDS ready

    float mx = 0.f;
    for (int c = 0; c < CMID; ++c) {
        int d1 = 0;
#pragma unroll
        for (int j = 0; j < 8; ++j) d1 = sdot4(wb[j], s_w1p[c*8 + j], d1);
        float j1 = 0.f;
        if (inb) {
            float d1f = (float)d1;
            if (s_fq1[384+c]) {
                j1 = qfast15(d1f, __uint_as_float(s_fq1[c]), __uint_as_float(s_fq1[192+c]));
            } else {
                float h1 = bnq(d1f, C1, gbn1[192+c], gbn1[c], gbn1[384+c]);
                j1 = qexact15(h1, s1v);
            }
        }
        jl[c & 1][t] = j1;
        __syncthreads();
        if (act) {
            const float* wd = s_wdw + c * 9;
            float d2 = 0.f;
#pragma unroll
            for (int dy = 0; dy < 3; ++dy)
#pragma unroll
                for (int dx = 0; dx < 3; ++dx)
                    d2 = fmaf(jl[c & 1][(ty+dy)*16 + tx+dx], wd[dy*3+dx], d2);
            float h2 = bnq(d2, C2, s_bn2[192+c], s_bn2[c], s_bn2[384+c]);
            mx = fmaxf(mx, h2);
        }
        if ((c & 7) == 7) {               // block-uniform early-exit check
            bool mine = act ? (mx >= 6.0f) : true;
            if (__all(mine) && (t & 63) == 0) atomicOr(&doneflag, 1u << (t >> 6));
            __syncthreads();
            if (doneflag == 0xFu) break;
        }
    }
    float r = bmax256(mx, red);
    if (t == 0) atomicMax((unsigned*)(ws + OFF_SCAL) + 2, __float_as_uint(r));
}

// full chain conv1(sdot4)->j1(fast)->dw->j2(fast)->conv2(sdot4)->bn3; h3->d_out; max|h3|
__global__ __launch_bounds__(256) void kconv2(unsigned char* __restrict__ ws,
                                              float* __restrict__ h3)
{
    __shared__ unsigned s_w1p[CMID*8];
    __shared__ float s_wdw[CMID*9];
    __shared__ unsigned s_w2p[48*COUT];
    __shared__ unsigned s_fq1[576];
    __shared__ unsigned s_fq2[576];
    __shared__ float s_bn3[96];
    __shared__ float jl[2][256];
    __shared__ float red[256];
    const int t = threadIdx.x;

    {
        const uint4* sp = (const uint4*)(ws + OFF_W1P);
        uint4* dp = (uint4*)s_w1p;
        for (int i = t; i < CMID*8/4; i += 256) dp[i] = sp[i];
        const float* wp = (const float*)(ws + OFF_WDW);
        for (int i = t; i < CMID*9; i += 256) s_wdw[i] = wp[i];
        const uint4* s2 = (const uint4*)(ws + OFF_W2P);
        uint4* d2 = (uint4*)s_w2p;
        for (int i = t; i < 48*COUT/4; i += 256) d2[i] = s2[i];
        const unsigned* f1 = (const unsigned*)(ws + OFF_FQ1);
        const unsigned* f2 = (const unsigned*)(ws + OFF_FQ2);
        for (int i = t; i < 576; i += 256) { s_fq1[i] = f1[i]; s_fq2[i] = f2[i]; }
        const float* b3p = (const float*)(ws + OFF_BN3);
        if (t < 96) s_bn3[t] = b3p[t];
    }

    const unsigned* scal = (const unsigned*)(ws + OFF_SCAL);
    const float* wsc = (const float*)(ws + OFF_WSC);
    const float* gbn1 = (const float*)(ws + OFF_BN1);
    const float* gbn2 = (const float*)(ws + OFF_BN2);
    const unsigned char* xq = ws + OFF_XQ;

    const float sx  = __uint_as_float(scal[0]) + 1e-8f;
    const float s1v = __uint_as_float(scal[1]) + 1e-8f;
    const float s2v = __uint_as_float(scal[2]) + 1e-8f;
    const float C1  = (float)(((double)sx  / 7.0)  * ((double)wsc[0] / 7.0));
    const float C2  = (float)(((double)s1v / 15.0) * ((double)wsc[1] / 7.0));
    const float C3  = (float)(((double)s2v / 15.0) * ((double)wsc[2] / 7.0));

    const int tile = blockIdx.x, n = blockIdx.y;
    const int ty = t >> 4, tx = t & 15;
    const int hy = (tile >> 3) * 14 - 1 + ty;
    const int wx = (tile & 7)  * 14 - 1 + tx;
    const bool inb = (hy >= 0 && hy < WID && wx >= 0 && wx < WID);
    const bool act = (ty < 14) && (tx < 14);

    unsigned wb[8];
    if (inb) {
        const uint4* q4 = (const uint4*)(xq + ((size_t)n * HW + hy * WID + wx) * 32);
        uint4 a = q4[0], b4 = q4[1];
        wb[0]=a.x; wb[1]=a.y; wb[2]=a.z; wb[3]=a.w;
        wb[4]=b4.x; wb[5]=b4.y; wb[6]=b4.z; wb[7]=b4.w;
    } else {
#pragma unroll
        for (int j = 0; j < 8; ++j) wb[j] = 0u;
    }
    __syncthreads();   // LDS ready

    int acc[COUT];
#pragma unroll
    for (int oc = 0; oc < COUT; ++oc) acc[oc] = 0;
    unsigned pj2 = 0u;

    for (int c = 0; c < CMID; ++c) {
        int d1 = 0;
#pragma unroll
        for (int j = 0; j < 8; ++j) d1 = sdot4(wb[j], s_w1p[c*8 + j], d1);
        float j1 = 0.f;
        if (inb) {
            float d1f = (float)d1;
            if (s_fq1[384+c]) {
                j1 = qfast15(d1f, __uint_as_float(s_fq1[c]), __uint_as_float(s_fq1[192+c]));
            } else {
                float h1 = bnq(d1f, C1, gbn1[192+c], gbn1[c], gbn1[384+c]);
                j1 = qexact15(h1, s1v);
            }
        }
        jl[c & 1][t] = j1;
        __syncthreads();
        if (act) {
            const float* wd = s_wdw + c * 9;
            float d2 = 0.f;
#pragma unroll
            for (int dy = 0; dy < 3; ++dy)
#pragma unroll
                for (int dx = 0; dx < 3; ++dx)
                    d2 = fmaf(jl[c & 1][(ty+dy)*16 + tx+dx], wd[dy*3+dx], d2);
            float j2;
            if (s_fq2[384+c]) {
                j2 = qfast15(d2, __uint_as_float(s_fq2[c]), __uint_as_float(s_fq2[192+c]));
            } else {
                float h2 = bnq(d2, C2, gbn2[192+c], gbn2[c], gbn2[384+c]);
                j2 = qexact15(h2, s2v);
            }
            pj2 |= ((unsigned)(int)j2) << (8 * (c & 3));
        }
        if ((c & 3) == 3) {
            const unsigned* w2r = s_w2p + (c >> 2) * COUT;
#pragma unroll
            for (int oc = 0; oc < COUT; ++oc) acc[oc] = sdot4(pj2, w2r[oc], acc[oc]);
            pj2 = 0u;
        }
    }

    float mx = 0.f;
    if (act) {
        const int gy = (tile >> 3) * 14 + ty;
        const int gx = (tile & 7)  * 14 + tx;
        const size_t base = (size_t)n * COUT * HW + gy * WID + gx;
#pragma unroll
        for (int oc = 0; oc < COUT; ++oc) {
            float y = __fmul_rn((float)acc[oc], C3);
            float h = __fadd_rn(__fmul_rn(__fsub_rn(y, s_bn3[32+oc]), s_bn3[oc]), s_bn3[64+oc]);
            h3[base + (size_t)oc * HW] = h;
            mx = fmaxf(mx, fabsf(h));
        }
    }
    float r = bmax256(mx, red);
    if (t == 0) atomicMax((unsigned*)(ws + OFF_SCAL) + 3, __float_as_uint(r));
}

// in-place on d_out: out = x + actq_signed(h3)
__global__ __launch_bounds__(256) void kout(const float4* __restrict__ x4,
                                            float4* __restrict__ io4,
                                            const unsigned char* __restrict__ ws)
{
    const unsigned* scal = (const unsigned*)(ws + OFF_SCAL);
    const float s3v = __uint_as_float(scal[3]) + 1e-8f;

    for (size_t i = (size_t)blockIdx.x*256 + threadIdx.x; i < NX/4; i += (size_t)gridDim.x*256) {
        float4 h = io4[i], xv = x4[i], o;
        float* hp = &h.x; float* xp = &xv.x; float* op = &o.x;
#pragma unroll
        for (int k = 0; k < 4; ++k) {
            float tq = fminf(fmaxf(hp[k] / s3v, -1.f), 1.f);
            float kq = rintf(__fmul_rn(tq, 7.f));
            float q  = __fmul_rn(kq / 7.f, s3v);
            op[k] = __fadd_rn(xp[k], q);
        }
        io4[i] = o;
    }
}

extern "C" void kernel_launch(void* const* d_in, const int* in_sizes, int n_in,
                              void* d_out, int out_size, void* d_ws, size_t ws_size,
                              hipStream_t stream)
{
    const float* x   = (const float*)d_in[0];
    const float* w1  = (const float*)d_in[1];
    const float* g1  = (const float*)d_in[2];
    const float* b1  = (const float*)d_in[3];
    const float* m1  = (const float*)d_in[4];
    const float* v1  = (const float*)d_in[5];
    const float* wdw = (const float*)d_in[6];
    const float* g2  = (const float*)d_in[7];
    const float* b2  = (const float*)d_in[8];
    const float* m2  = (const float*)d_in[9];
    const float* v2  = (const float*)d_in[10];
    const float* w2  = (const float*)d_in[11];
    const float* g3  = (const float*)d_in[12];
    const float* b3  = (const float*)d_in[13];
    const float* m3  = (const float*)d_in[14];
    const float* v3  = (const float*)d_in[15];
    unsigned char* ws = (unsigned char*)d_ws;

    hipLaunchKernelGGL(kprep, dim3(1), dim3(256), 0, stream,
                       w1, wdw, w2, g1, b1, m1, v1, g2, b2, m2, v2, g3, b3, m3, v3, ws);
    hipLaunchKernelGGL(kmaxx, dim3(2048), dim3(256), 0, stream, (const float4*)x, ws);
    hipLaunchKernelGGL(kmax1q, dim3(NPIX/256), dim3(256), 0, stream, x, ws);
    hipLaunchKernelGGL(kcoef, dim3(CMID), dim3(64), 0, stream, ws, 1);
    hipLaunchKernelGGL(kmax2, dim3(64, NB), dim3(256), 0, stream, ws);
    hipLaunchKernelGGL(kcoef, dim3(CMID), dim3(64), 0, stream, ws, 2);
    hipLaunchKernelGGL(kconv2, dim3(64, NB), dim3(256), 0, stream, ws, (float*)d_out);
    hipLaunchKernelGGL(kout, dim3(2048), dim3(256), 0, stream,
                       (const float4*)x, (float4*)d_out, ws);
}

// Round 5
// 389.457 us; speedup vs baseline: 2.5055x; 1.1399x over previous
//
#include <hip/hip_runtime.h>

// InvertedResidualQ on MI355X. Exact-integer quantized-conv formulation.
// R5: kconv2/kmax2 restructured into 8-channel phases (2 barriers/phase vs
// 1/channel -> 48 vs 192 barriers, 8-way ILP across channel chains);
// any-hit early exit on the clipped (cap=6) max scans.

#define HW    12544      // 112*112
#define WID   112
#define CIN   32
#define CMID  192
#define COUT  32
#define NB    32
#define NPIX  (NB*HW)        // 401408
#define NX    (NB*CIN*HW)    // 12845056

// workspace layout (bytes); ~12.9 MB total
#define OFF_SCAL   0         // 4 u32 atomic-max slots: sx, s1, s2, s3
#define OFF_WSC    16        // 3 f32 weight scales
#define OFF_BN1    64        // gi[192], m[192], b[192]
#define OFF_BN2    2368
#define OFF_BN3    4672      // gi[32], m[32], b[32]
#define OFF_W1P    5120      // 192*8 u32 packed i8 conv1 weights
#define OFF_WDW    11264     // 192*9 f32 dw codes
#define OFF_W2P    18176     // 48*32 u32 packed i8 conv2 weights [cgroup][oc]
#define OFF_FQ1    24320     // A[192] f32, B[192] f32, flag[192] u32
#define OFF_FQ2    26624     // same for stage 2
#define OFF_XQ     65536     // NPIX*32 i8 packed input codes, [pix][ic]

#if defined(__has_builtin)
#if __has_builtin(__builtin_amdgcn_sdot4)
#define HAVE_SDOT4 1
#endif
#endif

__device__ __forceinline__ int sdot4(unsigned a, unsigned b, int c) {
#ifdef HAVE_SDOT4
    return __builtin_amdgcn_sdot4((int)a, (int)b, c, false);
#else
    c += (int)(signed char)(a & 0xff)        * (int)(signed char)(b & 0xff);
    c += (int)(signed char)((a >> 8) & 0xff) * (int)(signed char)((b >> 8) & 0xff);
    c += (int)(signed char)((a >> 16) & 0xff)* (int)(signed char)((b >> 16) & 0xff);
    c += (int)(signed char)(a >> 24)         * (int)(signed char)(b >> 24);
    return c;
#endif
}

__device__ __forceinline__ float bmax256(float v, float* red) {
    const int t = threadIdx.x;
    red[t] = v; __syncthreads();
    for (int s = 128; s; s >>= 1) {
        if (t < s) red[t] = fmaxf(red[t], red[t + s]);
        __syncthreads();
    }
    float r = red[0]; __syncthreads();
    return r;
}

// round(clip(x/s, lo, 1) * n), half-even like jnp.round
__device__ __forceinline__ float qcode(float x, float s, float n, float lo) {
    float t = x / s;
    t = fminf(fmaxf(t, lo), 1.0f);
    return rintf(__fmul_rn(t, n));
}

// bn + relu6, identical instruction sequence wherever used (bit-exact recompute)
__device__ __forceinline__ float bnq(float d, float C, float m, float g, float b) {
    float y = __fmul_rn(d, C);
    float h = __fadd_rn(__fmul_rn(__fsub_rn(y, m), g), b);
    return fminf(fmaxf(h, 0.f), 6.f);
}

// exact quantization of (already relu6'd) h against scale s: rint(min(h/s,1)*15)
__device__ __forceinline__ float qexact15(float h, float s) {
    return rintf(__fmul_rn(fminf(h / s, 1.f), 15.f));
}
// fast affine quantization (verified per channel in kcoef)
__device__ __forceinline__ float qfast15(float df, float A, float B) {
    float t = fmaf(df, A, B);
    return rintf(fminf(fmaxf(t, 0.f), 15.f));
}

__global__ __launch_bounds__(256) void kprep(
    const float* __restrict__ w1, const float* __restrict__ wdw, const float* __restrict__ w2,
    const float* __restrict__ g1, const float* __restrict__ b1, const float* __restrict__ m1, const float* __restrict__ v1,
    const float* __restrict__ g2, const float* __restrict__ b2, const float* __restrict__ m2, const float* __restrict__ v2,
    const float* __restrict__ g3, const float* __restrict__ b3, const float* __restrict__ m3, const float* __restrict__ v3,
    unsigned char* __restrict__ ws)
{
    __shared__ float red[256];
    const int t = threadIdx.x;
    unsigned* scal = (unsigned*)(ws + OFF_SCAL);
    float* wsc  = (float*)(ws + OFF_WSC);
    float* bn1  = (float*)(ws + OFF_BN1);
    float* bn2  = (float*)(ws + OFF_BN2);
    float* bn3  = (float*)(ws + OFF_BN3);
    unsigned* w1p = (unsigned*)(ws + OFF_W1P);
    float*  wdwf  = (float*)(ws + OFF_WDW);
    unsigned* w2p = (unsigned*)(ws + OFF_W2P);

    if (t < 4) scal[t] = 0u;   // reset atomic-max slots (deterministic replay)

    float m;
    m = 0.f; for (int i = t; i < CMID*CIN; i += 256) m = fmaxf(m, fabsf(w1[i]));
    float sw1 = bmax256(m, red) + 1e-8f;
    m = 0.f; for (int i = t; i < CMID*9; i += 256) m = fmaxf(m, fabsf(wdw[i]));
    float swd = bmax256(m, red) + 1e-8f;
    m = 0.f; for (int i = t; i < COUT*CMID; i += 256) m = fmaxf(m, fabsf(w2[i]));
    float sw2 = bmax256(m, red) + 1e-8f;
    if (t == 0) { wsc[0] = sw1; wsc[1] = swd; wsc[2] = sw2; }

    // packed i8 conv1 weights: word (oc,j) holds ic = 4j..4j+3
    for (int i = t; i < CMID*8; i += 256) {
        int oc = i >> 3, j = i & 7;
        unsigned wword = 0;
#pragma unroll
        for (int k = 0; k < 4; ++k) {
            int code = (int)qcode(w1[oc*CIN + 4*j + k], sw1, 7.f, -1.f);
            wword |= ((unsigned)code & 0xffu) << (8*k);
        }
        w1p[i] = wword;
    }
    for (int i = t; i < CMID*9; i += 256) wdwf[i] = qcode(wdw[i], swd, 7.f, -1.f);
    // packed i8 conv2 weights: word (cg,oc) byte k = channel 4cg+k of output oc
    for (int i = t; i < 48*COUT; i += 256) {
        int cg = i >> 5, oc = i & 31;
        unsigned wword = 0;
#pragma unroll
        for (int k = 0; k < 4; ++k) {
            int code = (int)qcode(w2[oc*CMID + 4*cg + k], sw2, 7.f, -1.f);
            wword |= ((unsigned)code & 0xffu) << (8*k);
        }
        w2p[i] = wword;
    }

    for (int c = t; c < CMID; c += 256) {
        float vv1 = v1[c] + 1e-5f;
        bn1[c] = __fmul_rn(g1[c], (float)(1.0 / sqrt((double)vv1)));
        bn1[192+c] = m1[c]; bn1[384+c] = b1[c];
        float vv2 = v2[c] + 1e-5f;
        bn2[c] = __fmul_rn(g2[c], (float)(1.0 / sqrt((double)vv2)));
        bn2[192+c] = m2[c]; bn2[384+c] = b2[c];
    }
    for (int c = t; c < COUT; c += 256) {
        float vv3 = v3[c] + 1e-5f;
        bn3[c] = __fmul_rn(g3[c], (float)(1.0 / sqrt((double)vv3)));
        bn3[32+c] = m3[c]; bn3[64+c] = b3[c];
    }
}

__global__ __launch_bounds__(256) void kmaxx(const float4* __restrict__ x4,
                                             unsigned char* __restrict__ ws)
{
    __shared__ float red[256];
    float m = 0.f;
    for (size_t i = (size_t)blockIdx.x*256 + threadIdx.x; i < NX/4; i += (size_t)gridDim.x*256) {
        float4 v = x4[i];
        m = fmaxf(m, fmaxf(fmaxf(fabsf(v.x), fabsf(v.y)), fmaxf(fabsf(v.z), fabsf(v.w))));
    }
    float r = bmax256(m, red);
    if (threadIdx.x == 0) atomicMax((unsigned*)(ws + OFF_SCAL), __float_as_uint(r));
}

// quantize x -> xq packed codes; conv1 max-scan (sdot4) with wave ANY-exit
// (h1 clipped at 6 -> once any lane caps, the wave's contribution is settled)
__global__ __launch_bounds__(256) void kmax1q(const float* __restrict__ x,
                                              unsigned char* __restrict__ ws)
{
    __shared__ unsigned s_w1p[CMID*8];
    __shared__ float s_bn1[576];
    __shared__ float red[256];
    const int t = threadIdx.x;

    {
        const uint4* src = (const uint4*)(ws + OFF_W1P);
        uint4* dst = (uint4*)s_w1p;
        for (int i = t; i < CMID*8/4; i += 256) dst[i] = src[i];
        const float* b = (const float*)(ws + OFF_BN1);
        for (int i = t; i < 576; i += 256) s_bn1[i] = b[i];
    }

    const unsigned* scal = (const unsigned*)(ws + OFF_SCAL);
    const float* wsc = (const float*)(ws + OFF_WSC);
    unsigned char* xq = ws + OFF_XQ;

    const float sx = __uint_as_float(scal[0]) + 1e-8f;
    const float C1 = (float)(((double)sx / 7.0) * ((double)wsc[0] / 7.0));

    const int p = blockIdx.x * 256 + t;
    const int n = p / HW, pi = p % HW;
    const float* xp = x + (size_t)n * CIN * HW + pi;

    float kx[CIN];
#pragma unroll
    for (int ic = 0; ic < CIN; ++ic) {
        float v = xp[(size_t)ic * HW] / sx;
        v = fminf(fmaxf(v, -1.f), 1.f);
        kx[ic] = rintf(__fmul_rn(v, 7.f));
    }

    unsigned wb[8];
#pragma unroll
    for (int j = 0; j < 8; ++j) {
        unsigned b0 = (unsigned)(int)kx[4*j]     & 0xffu;
        unsigned b1 = (unsigned)(int)kx[4*j + 1] & 0xffu;
        unsigned b2 = (unsigned)(int)kx[4*j + 2] & 0xffu;
        unsigned b3 = (unsigned)(int)kx[4*j + 3] & 0xffu;
        wb[j] = b0 | (b1 << 8) | (b2 << 16) | (b3 << 24);
    }
    uint4* q4 = (uint4*)(xq + (size_t)p * 32);
    q4[0] = make_uint4(wb[0], wb[1], wb[2], wb[3]);
    q4[1] = make_uint4(wb[4], wb[5], wb[6], wb[7]);

    __syncthreads();   // LDS tables ready

    float mx = 0.f;
    for (int oc = 0; oc < CMID; ++oc) {
        int d = 0;
#pragma unroll
        for (int j = 0; j < 8; ++j) d = sdot4(wb[j], s_w1p[oc*8 + j], d);
        float h = bnq((float)d, C1, s_bn1[192+oc], s_bn1[oc], s_bn1[384+oc]);
        mx = fmaxf(mx, h);
        if (__any(mx >= 6.0f)) break;    // any lane capped -> wave max settled (=6)
    }
    float r = bmax256(mx, red);
    if (t == 0) atomicMax((unsigned*)(ws + OFF_SCAL) + 1, __float_as_uint(r));
}

// per-channel fast-quant coefficients + EXHAUSTIVE bit-exactness verification
// over the full integer dot domain. stage 1: j1(d1), stage 2: j2(d2).
__global__ __launch_bounds__(64) void kcoef(unsigned char* __restrict__ ws, int stage)
{
    const unsigned* scal = (const unsigned*)(ws + OFF_SCAL);
    const float* wsc = (const float*)(ws + OFF_WSC);
    const int c = blockIdx.x, lane = threadIdx.x;
    const float* bn = (const float*)(ws + (stage == 1 ? OFF_BN1 : OFF_BN2));
    float* fq = (float*)(ws + (stage == 1 ? OFF_FQ1 : OFF_FQ2));

    float C, s; int R;
    if (stage == 1) {
        float sx = __uint_as_float(scal[0]) + 1e-8f;
        C = (float)(((double)sx / 7.0) * ((double)wsc[0] / 7.0));
        s = __uint_as_float(scal[1]) + 1e-8f;
        R = 1568;                          // |d1| <= 32*7*7
    } else {
        float s1 = __uint_as_float(scal[1]) + 1e-8f;
        C = (float)(((double)s1 / 15.0) * ((double)wsc[1] / 7.0));
        s = __uint_as_float(scal[2]) + 1e-8f;
        R = 945;                           // |d2| <= 9*15*7
    }
    const float gi = bn[c], mm = bn[192+c], bb = bn[384+c];
    const float A = (float)((double)C * (double)gi * 15.0 / (double)s);
    const float B = (float)(((double)bb - (double)mm * (double)gi) * 15.0 / (double)s);

    bool bad = false;
    for (int d = -R + lane; d <= R; d += 64) {
        float df = (float)d;
        float je = qexact15(bnq(df, C, mm, gi, bb), s);
        float jf = qfast15(df, A, B);
        if (je != jf) bad = true;
    }
    bool any = __any(bad);
    if (lane == 0) {
        fq[c] = A; fq[192+c] = B;
        ((unsigned*)fq)[384+c] = any ? 0u : 1u;   // 1 = fast path verified
    }
}

// tile 14x14 out, halo 16x16 = 256 = blockDim. 8-channel phases:
// part1 conv1(sdot4)->j1 for 8 ch (ILP), barrier, part2 dw for 8 ch,
// barrier; block ANY-hit early exit (cap 6).
__global__ __launch_bounds__(256) void kmax2(unsigned char* __restrict__ ws)
{
    __shared__ unsigned s_w1p[CMID*8];
    __shared__ float s_wdw[CMID*9];
    __shared__ float s_bn2[576];
    __shared__ unsigned s_fq1[576];        // A,B (f32 bits), flag
    __shared__ float jl[8][256];
    __shared__ float red[256];
    __shared__ unsigned s_flag;
    const int t = threadIdx.x;

    {
        const uint4* sp = (const uint4*)(ws + OFF_W1P);
        uint4* dp = (uint4*)s_w1p;
        for (int i = t; i < CMID*8/4; i += 256) dp[i] = sp[i];
        const float* wp = (const float*)(ws + OFF_WDW);
        for (int i = t; i < CMID*9; i += 256) s_wdw[i] = wp[i];
        const float* b2p = (const float*)(ws + OFF_BN2);
        for (int i = t; i < 576; i += 256) s_bn2[i] = b2p[i];
        const unsigned* fp = (const unsigned*)(ws + OFF_FQ1);
        for (int i = t; i < 576; i += 256) s_fq1[i] = fp[i];
        if (t == 0) s_flag = 0u;
    }

    const unsigned* scal = (const unsigned*)(ws + OFF_SCAL);
    const float* wsc = (const float*)(ws + OFF_WSC);
    const float* gbn1 = (const float*)(ws + OFF_BN1);
    const unsigned char* xq = ws + OFF_XQ;

    const float sx  = __uint_as_float(scal[0]) + 1e-8f;
    const float s1v = __uint_as_float(scal[1]) + 1e-8f;
    const float C1  = (float)(((double)sx  / 7.0)  * ((double)wsc[0] / 7.0));
    const float C2  = (float)(((double)s1v / 15.0) * ((double)wsc[1] / 7.0));

    const int tile = blockIdx.x, n = blockIdx.y;
    const int ty = t >> 4, tx = t & 15;
    const int hy = (tile >> 3) * 14 - 1 + ty;
    const int wx = (tile & 7)  * 14 - 1 + tx;
    const bool inb = (hy >= 0 && hy < WID && wx >= 0 && wx < WID);
    const bool act = (ty < 14) && (tx < 14);

    unsigned wb[8];
    if (inb) {
        const uint4* q4 = (const uint4*)(xq + ((size_t)n * HW + hy * WID + wx) * 32);
        uint4 a = q4[0], b4 = q4[1];
        wb[0]=a.x; wb[1]=a.y; wb[2]=a.z; wb[3]=a.w;
        wb[4]=b4.x; wb[5]=b4.y; wb[6]=b4.z; wb[7]=b4.w;
    } else {
#pragma unroll
        for (int j = 0; j < 8; ++j) wb[j] = 0u;
    }
    __syncthreads();   // LDS ready

    float mx = 0.f;
    for (int ph = 0; ph < CMID/8; ++ph) {
#pragma unroll
        for (int k = 0; k < 8; ++k) {      // 8 independent conv1 chains (ILP)
            const int c = ph*8 + k;
            int d1 = 0;
#pragma unroll
            for (int j = 0; j < 8; ++j) d1 = sdot4(wb[j], s_w1p[c*8 + j], d1);
            float j1 = 0.f;
            if (inb) {
                float d1f = (float)d1;
                if (s_fq1[384+c]) {
                    j1 = qfast15(d1f, __uint_as_float(s_fq1[c]), __uint_as_float(s_fq1[192+c]));
                } else {
                    float h1 = bnq(d1f, C1, gbn1[192+c], gbn1[c], gbn1[384+c]);
                    j1 = qexact15(h1, s1v);
                }
            }
            jl[k][t] = j1;
        }
        __syncthreads();
        if (act) {
#pragma unroll
            for (int k = 0; k < 8; ++k) {
                const int c = ph*8 + k;
                const float* wd = s_wdw + c * 9;
                float d2 = 0.f;
#pragma unroll
                for (int dy = 0; dy < 3; ++dy)
#pragma unroll
                    for (int dx = 0; dx < 3; ++dx)
                        d2 = fmaf(jl[k][(ty+dy)*16 + tx+dx], wd[dy*3+dx], d2);
                float h2 = bnq(d2, C2, s_bn2[192+c], s_bn2[c], s_bn2[384+c]);
                mx = fmaxf(mx, h2);
            }
        }
        if (mx >= 6.0f) s_flag = 1u;       // benign race; visible after barrier
        __syncthreads();
        if (s_flag) break;                 // block max settled at cap (=6)
    }
    float r = bmax256(mx, red);
    if (t == 0) atomicMax((unsigned*)(ws + OFF_SCAL) + 2, __float_as_uint(r));
}

// full chain, 8-channel phases: conv1(sdot4)->j1(fast) | barrier | dw->j2(fast)
// ->conv2(sdot4) | barrier. h3 -> d_out; max|h3|.
__global__ __launch_bounds__(256) void kconv2(unsigned char* __restrict__ ws,
                                              float* __restrict__ h3)
{
    __shared__ unsigned s_w1p[CMID*8];
    __shared__ float s_wdw[CMID*9];
    __shared__ unsigned s_w2p[48*COUT];
    __shared__ unsigned s_fq1[576];
    __shared__ unsigned s_fq2[576];
    __shared__ float s_bn3[96];
    __shared__ float jl[8][256];
    __shared__ float red[256];
    const int t = threadIdx.x;

    {
        const uint4* sp = (const uint4*)(ws + OFF_W1P);
        uint4* dp = (uint4*)s_w1p;
        for (int i = t; i < CMID*8/4; i += 256) dp[i] = sp[i];
        const float* wp = (const float*)(ws + OFF_WDW);
        for (int i = t; i < CMID*9; i += 256) s_wdw[i] = wp[i];
        const uint4* s2 = (const uint4*)(ws + OFF_W2P);
        uint4* d2 = (uint4*)s_w2p;
        for (int i = t; i < 48*COUT/4; i += 256) d2[i] = s2[i];
        const unsigned* f1 = (const unsigned*)(ws + OFF_FQ1);
        const unsigned* f2 = (const unsigned*)(ws + OFF_FQ2);
        for (int i = t; i < 576; i += 256) { s_fq1[i] = f1[i]; s_fq2[i] = f2[i]; }
        const float* b3p = (const float*)(ws + OFF_BN3);
        if (t < 96) s_bn3[t] = b3p[t];
    }

    const unsigned* scal = (const unsigned*)(ws + OFF_SCAL);
    const float* wsc = (const float*)(ws + OFF_WSC);
    const float* gbn1 = (const float*)(ws + OFF_BN1);
    const float* gbn2 = (const float*)(ws + OFF_BN2);
    const unsigned char* xq = ws + OFF_XQ;

    const float sx  = __uint_as_float(scal[0]) + 1e-8f;
    const float s1v = __uint_as_float(scal[1]) + 1e-8f;
    const float s2v = __uint_as_float(scal[2]) + 1e-8f;
    const float C1  = (float)(((double)sx  / 7.0)  * ((double)wsc[0] / 7.0));
    const float C2  = (float)(((double)s1v / 15.0) * ((double)wsc[1] / 7.0));
    const float C3  = (float)(((double)s2v / 15.0) * ((double)wsc[2] / 7.0));

    const int tile = blockIdx.x, n = blockIdx.y;
    const int ty = t >> 4, tx = t & 15;
    const int hy = (tile >> 3) * 14 - 1 + ty;
    const int wx = (tile & 7)  * 14 - 1 + tx;
    const bool inb = (hy >= 0 && hy < WID && wx >= 0 && wx < WID);
    const bool act = (ty < 14) && (tx < 14);

    unsigned wb[8];
    if (inb) {
        const uint4* q4 = (const uint4*)(xq + ((size_t)n * HW + hy * WID + wx) * 32);
        uint4 a = q4[0], b4 = q4[1];
        wb[0]=a.x; wb[1]=a.y; wb[2]=a.z; wb[3]=a.w;
        wb[4]=b4.x; wb[5]=b4.y; wb[6]=b4.z; wb[7]=b4.w;
    } else {
#pragma unroll
        for (int j = 0; j < 8; ++j) wb[j] = 0u;
    }
    __syncthreads();   // LDS ready

    int acc[COUT];
#pragma unroll
    for (int oc = 0; oc < COUT; ++oc) acc[oc] = 0;

    for (int ph = 0; ph < CMID/8; ++ph) {
#pragma unroll
        for (int k = 0; k < 8; ++k) {      // 8 independent conv1 chains (ILP)
            const int c = ph*8 + k;
            int d1 = 0;
#pragma unroll
            for (int j = 0; j < 8; ++j) d1 = sdot4(wb[j], s_w1p[c*8 + j], d1);
            float j1 = 0.f;
            if (inb) {
                float d1f = (float)d1;
                if (s_fq1[384+c]) {
                    j1 = qfast15(d1f, __uint_as_float(s_fq1[c]), __uint_as_float(s_fq1[192+c]));
                } else {
                    float h1 = bnq(d1f, C1, gbn1[192+c], gbn1[c], gbn1[384+c]);
                    j1 = qexact15(h1, s1v);
                }
            }
            jl[k][t] = j1;
        }
        __syncthreads();
        if (act) {
            unsigned pj2 = 0u;
#pragma unroll
            for (int k = 0; k < 8; ++k) {
                const int c = ph*8 + k;
                const float* wd = s_wdw + c * 9;
                float d2 = 0.f;
#pragma unroll
                for (int dy = 0; dy < 3; ++dy)
#pragma unroll
                    for (int dx = 0; dx < 3; ++dx)
                        d2 = fmaf(jl[k][(ty+dy)*16 + tx+dx], wd[dy*3+dx], d2);
                float j2;
                if (s_fq2[384+c]) {
                    j2 = qfast15(d2, __uint_as_float(s_fq2[c]), __uint_as_float(s_fq2[192+c]));
                } else {
                    float h2 = bnq(d2, C2, gbn2[192+c], gbn2[c], gbn2[384+c]);
                    j2 = qexact15(h2, s2v);
                }
                pj2 |= ((unsigned)(int)j2) << (8 * (k & 3));
                if ((k & 3) == 3) {
                    const unsigned* w2r = s_w2p + ((ph*8 + k) >> 2) * COUT;
#pragma unroll
                    for (int oc = 0; oc < COUT; ++oc) acc[oc] = sdot4(pj2, w2r[oc], acc[oc]);
                    pj2 = 0u;
                }
            }
        }
        __syncthreads();                   // protect jl before next phase
    }

    float mx = 0.f;
    if (act) {
        const int gy = (tile >> 3) * 14 + ty;
        const int gx = (tile & 7)  * 14 + tx;
        const size_t base = (size_t)n * COUT * HW + gy * WID + gx;
#pragma unroll
        for (int oc = 0; oc < COUT; ++oc) {
            float y = __fmul_rn((float)acc[oc], C3);
            float h = __fadd_rn(__fmul_rn(__fsub_rn(y, s_bn3[32+oc]), s_bn3[oc]), s_bn3[64+oc]);
            h3[base + (size_t)oc * HW] = h;
            mx = fmaxf(mx, fabsf(h));
        }
    }
    float r = bmax256(mx, red);
    if (t == 0) atomicMax((unsigned*)(ws + OFF_SCAL) + 3, __float_as_uint(r));
}

// in-place on d_out: out = x + actq_signed(h3)
__global__ __launch_bounds__(256) void kout(const float4* __restrict__ x4,
                                            float4* __restrict__ io4,
                                            const unsigned char* __restrict__ ws)
{
    const unsigned* scal = (const unsigned*)(ws + OFF_SCAL);
    const float s3v = __uint_as_float(scal[3]) + 1e-8f;

    for (size_t i = (size_t)blockIdx.x*256 + threadIdx.x; i < NX/4; i += (size_t)gridDim.x*256) {
        float4 h = io4[i], xv = x4[i], o;
        float* hp = &h.x; float* xp = &xv.x; float* op = &o.x;
#pragma unroll
        for (int k = 0; k < 4; ++k) {
            float tq = fminf(fmaxf(hp[k] / s3v, -1.f), 1.f);
            float kq = rintf(__fmul_rn(tq, 7.f));
            float q  = __fmul_rn(kq / 7.f, s3v);
            op[k] = __fadd_rn(xp[k], q);
        }
        io4[i] = o;
    }
}

extern "C" void kernel_launch(void* const* d_in, const int* in_sizes, int n_in,
                              void* d_out, int out_size, void* d_ws, size_t ws_size,
                              hipStream_t stream)
{
    const float* x   = (const float*)d_in[0];
    const float* w1  = (const float*)d_in[1];
    const float* g1  = (const float*)d_in[2];
    const float* b1  = (const float*)d_in[3];
    const float* m1  = (const float*)d_in[4];
    const float* v1  = (const float*)d_in[5];
    const float* wdw = (const float*)d_in[6];
    const float* g2  = (const float*)d_in[7];
    const float* b2  = (const float*)d_in[8];
    const float* m2  = (const float*)d_in[9];
    const float* v2  = (const float*)d_in[10];
    const float* w2  = (const float*)d_in[11];
    const float* g3  = (const float*)d_in[12];
    const float* b3  = (const float*)d_in[13];
    const float* m3  = (const float*)d_in[14];
    const float* v3  = (const float*)d_in[15];
    unsigned char* ws = (unsigned char*)d_ws;

    hipLaunchKernelGGL(kprep, dim3(1), dim3(256), 0, stream,
                       w1, wdw, w2, g1, b1, m1, v1, g2, b2, m2, v2, g3, b3, m3, v3, ws);
    hipLaunchKernelGGL(kmaxx, dim3(2048), dim3(256), 0, stream, (const float4*)x, ws);
    hipLaunchKernelGGL(kmax1q, dim3(NPIX/256), dim3(256), 0, stream, x, ws);
    hipLaunchKernelGGL(kcoef, dim3(CMID), dim3(64), 0, stream, ws, 1);
    hipLaunchKernelGGL(kmax2, dim3(64, NB), dim3(256), 0, stream, ws);
    hipLaunchKernelGGL(kcoef, dim3(CMID), dim3(64), 0, stream, ws, 2);
    hipLaunchKernelGGL(kconv2, dim3(64, NB), dim3(256), 0, stream, ws, (float*)d_out);
    hipLaunchKernelGGL(kout, dim3(2048), dim3(256), 0, stream,
                       (const float4*)x, (float4*)d_out, ws);
}

// Round 6
// 279.282 us; speedup vs baseline: 3.4939x; 1.3945x over previous
//
#include <hip/hip_runtime.h>

// InvertedResidualQ on MI355X. Exact-integer quantized-conv formulation.
// R6: conv1 + conv2 moved to i8 MFMA (mfma_i32_16x16x32_i8, swapped operands
// so C cols = pixels, C rows = oc). dw on float4 quad-packed channels.
// Numerics bit-identical: integer dots are exact; quant chains unchanged
// (kcoef exhaustively verifies fast affine quant; exact fallback otherwise).

#define HW    12544      // 112*112
#define WID   112
#define CIN   32
#define CMID  192
#define COUT  32
#define NB    32
#define NPIX  (NB*HW)        // 401408
#define NX    (NB*CIN*HW)    // 12845056

// workspace layout (bytes)
#define OFF_SCAL   0         // 4 u32: [0]=sx (plain store), 1..3 atomic-max s1,s2,s3
#define OFF_WSC    16        // 3 f32 weight scales
#define OFF_BN1    64        // gi[192], m[192], b[192]
#define OFF_BN2    2368
#define OFF_BN3    4672      // gi[32], m[32], b[32] (384B)
#define OFF_FQ1    5120      // A[192],B[192] f32, flag[192] u32, allfast u32 (2308B)
#define OFF_FQ2    7488
#define OFF_W1P    9856      // 192*8 u32 packed i8 conv1 weights (sdot4 path)
#define OFF_WDW    16000     // 192*9 f32 dw codes (kmax2)
#define OFF_W1A    22912     // 12*64*8B conv1 A-fragments
#define OFF_W2A    29056     // 2*6*64*8B conv2 A-fragments
#define OFF_WDWT   35200     // 48*9 float4 dw weights transposed (6912B)
#define OFF_PMAX   42112     // 2048 f32 per-block |x| partial maxes
#define OFF_XQ     65536     // NPIX*32 i8 packed input codes, [pix][ic]

typedef int v4i __attribute__((ext_vector_type(4)));
typedef unsigned long long ull;

#if defined(__has_builtin)
#if __has_builtin(__builtin_amdgcn_sdot4)
#define HAVE_SDOT4 1
#endif
#endif

__device__ __forceinline__ int sdot4(unsigned a, unsigned b, int c) {
#ifdef HAVE_SDOT4
    return __builtin_amdgcn_sdot4((int)a, (int)b, c, false);
#else
    c += (int)(signed char)(a & 0xff)        * (int)(signed char)(b & 0xff);
    c += (int)(signed char)((a >> 8) & 0xff) * (int)(signed char)((b >> 8) & 0xff);
    c += (int)(signed char)((a >> 16) & 0xff)* (int)(signed char)((b >> 16) & 0xff);
    c += (int)(signed char)(a >> 24)         * (int)(signed char)(b >> 24);
    return c;
#endif
}

__device__ __forceinline__ v4i mfma_i8(ull a, ull b, v4i c) {
    return __builtin_amdgcn_mfma_i32_16x16x32_i8((long)a, (long)b, c, 0, 0, 0);
}

__device__ __forceinline__ float bmax256(float v, float* red) {
    const int t = threadIdx.x;
    red[t] = v; __syncthreads();
    for (int s = 128; s; s >>= 1) {
        if (t < s) red[t] = fmaxf(red[t], red[t + s]);
        __syncthreads();
    }
    float r = red[0]; __syncthreads();
    return r;
}

__device__ __forceinline__ float qcode(float x, float s, float n, float lo) {
    float t = x / s;
    t = fminf(fmaxf(t, lo), 1.0f);
    return rintf(__fmul_rn(t, n));
}

__device__ __forceinline__ float bnq(float d, float C, float m, float g, float b) {
    float y = __fmul_rn(d, C);
    float h = __fadd_rn(__fmul_rn(__fsub_rn(y, m), g), b);
    return fminf(fmaxf(h, 0.f), 6.f);
}

__device__ __forceinline__ float qexact15(float h, float s) {
    return rintf(__fmul_rn(fminf(h / s, 1.f), 15.f));
}
__device__ __forceinline__ float qfast15(float df, float A, float B) {
    float t = fmaf(df, A, B);
    return rintf(fminf(fmaxf(t, 0.f), 15.f));
}

// merged prep (block 0) + |x| partial max (all blocks -> pmax[block])
__global__ __launch_bounds__(256) void kprepx(
    const float4* __restrict__ x4,
    const float* __restrict__ w1, const float* __restrict__ wdw, const float* __restrict__ w2,
    const float* __restrict__ g1, const float* __restrict__ b1, const float* __restrict__ m1, const float* __restrict__ v1,
    const float* __restrict__ g2, const float* __restrict__ b2, const float* __restrict__ m2, const float* __restrict__ v2,
    const float* __restrict__ g3, const float* __restrict__ b3, const float* __restrict__ m3, const float* __restrict__ v3,
    unsigned char* __restrict__ ws)
{
    __shared__ float red[256];
    const int t = threadIdx.x;

    if (blockIdx.x == 0) {
        unsigned* scal = (unsigned*)(ws + OFF_SCAL);
        float* wsc  = (float*)(ws + OFF_WSC);
        float* bn1  = (float*)(ws + OFF_BN1);
        float* bn2  = (float*)(ws + OFF_BN2);
        float* bn3  = (float*)(ws + OFF_BN3);
        unsigned* w1p = (unsigned*)(ws + OFF_W1P);
        float*  wdwf  = (float*)(ws + OFF_WDW);

        if (t < 4) scal[t] = 0u;
        if (t == 0) { ((unsigned*)(ws+OFF_FQ1))[576] = 1u; ((unsigned*)(ws+OFF_FQ2))[576] = 1u; }

        float m;
        m = 0.f; for (int i = t; i < CMID*CIN; i += 256) m = fmaxf(m, fabsf(w1[i]));
        float sw1 = bmax256(m, red) + 1e-8f;
        m = 0.f; for (int i = t; i < CMID*9; i += 256) m = fmaxf(m, fabsf(wdw[i]));
        float swd = bmax256(m, red) + 1e-8f;
        m = 0.f; for (int i = t; i < COUT*CMID; i += 256) m = fmaxf(m, fabsf(w2[i]));
        float sw2 = bmax256(m, red) + 1e-8f;
        if (t == 0) { wsc[0] = sw1; wsc[1] = swd; wsc[2] = sw2; }

        // packed i8 conv1 weights (sdot4 path, kmax1q/kmax2)
        for (int i = t; i < CMID*8; i += 256) {
            int oc = i >> 3, j = i & 7;
            unsigned wword = 0;
#pragma unroll
            for (int k = 0; k < 4; ++k) {
                int code = (int)qcode(w1[oc*CIN + 4*j + k], sw1, 7.f, -1.f);
                wword |= ((unsigned)code & 0xffu) << (8*k);
            }
            w1p[i] = wword;
        }
        for (int i = t; i < CMID*9; i += 256) wdwf[i] = qcode(wdw[i], swd, 7.f, -1.f);

        // conv1 A-fragments: [octile][lane] 8B, oc = octile*16+(l&15), ic = (l>>4)*8+e
        for (int i = t; i < 12*64; i += 256) {
            int octile = i >> 6, l = i & 63;
            int oc = octile*16 + (l & 15), icb = (l >> 4) * 8;
            unsigned lo = 0, hi = 0;
#pragma unroll
            for (int k = 0; k < 4; ++k) {
                lo |= ((unsigned)(int)qcode(w1[oc*CIN + icb + k],     sw1, 7.f, -1.f) & 0xffu) << (8*k);
                hi |= ((unsigned)(int)qcode(w1[oc*CIN + icb + 4 + k], sw1, 7.f, -1.f) & 0xffu) << (8*k);
            }
            ((unsigned*)(ws + OFF_W1A))[i*2]   = lo;
            ((unsigned*)(ws + OFF_W1A))[i*2+1] = hi;
        }
        // conv2 A-fragments: [oct][chunk][lane] 8B, oc = oct*16+(l&15), ch = chunk*32+(l>>4)*8+e
        for (int i = t; i < 2*6*64; i += 256) {
            int oct = i / 384, rem = i % 384, chunk = rem >> 6, l = rem & 63;
            int oc = oct*16 + (l & 15), cb = chunk*32 + (l >> 4) * 8;
            unsigned lo = 0, hi = 0;
#pragma unroll
            for (int k = 0; k < 4; ++k) {
                lo |= ((unsigned)(int)qcode(w2[oc*CMID + cb + k],     sw2, 7.f, -1.f) & 0xffu) << (8*k);
                hi |= ((unsigned)(int)qcode(w2[oc*CMID + cb + 4 + k], sw2, 7.f, -1.f) & 0xffu) << (8*k);
            }
            ((unsigned*)(ws + OFF_W2A))[i*2]   = lo;
            ((unsigned*)(ws + OFF_W2A))[i*2+1] = hi;
        }
        // dw weights transposed to quads: [qg][tap] float4 over channels qg*4+r
        for (int i = t; i < 48*9; i += 256) {
            int qg = i / 9, tap = i % 9;
            float4 v;
            v.x = qcode(wdw[(qg*4+0)*9 + tap], swd, 7.f, -1.f);
            v.y = qcode(wdw[(qg*4+1)*9 + tap], swd, 7.f, -1.f);
            v.z = qcode(wdw[(qg*4+2)*9 + tap], swd, 7.f, -1.f);
            v.w = qcode(wdw[(qg*4+3)*9 + tap], swd, 7.f, -1.f);
            ((float4*)(ws + OFF_WDWT))[i] = v;
        }

        for (int c = t; c < CMID; c += 256) {
            float vv1 = v1[c] + 1e-5f;
            bn1[c] = __fmul_rn(g1[c], (float)(1.0 / sqrt((double)vv1)));
            bn1[192+c] = m1[c]; bn1[384+c] = b1[c];
            float vv2 = v2[c] + 1e-5f;
            bn2[c] = __fmul_rn(g2[c], (float)(1.0 / sqrt((double)vv2)));
            bn2[192+c] = m2[c]; bn2[384+c] = b2[c];
        }
        for (int c = t; c < COUT; c += 256) {
            float vv3 = v3[c] + 1e-5f;
            bn3[c] = __fmul_rn(g3[c], (float)(1.0 / sqrt((double)vv3)));
            bn3[32+c] = m3[c]; bn3[64+c] = b3[c];
        }
    }

    // |x| partial max -> pmax[blockIdx.x] (plain store, no reset race)
    float m = 0.f;
    for (size_t i = (size_t)blockIdx.x*256 + t; i < NX/4; i += (size_t)gridDim.x*256) {
        float4 v = x4[i];
        m = fmaxf(m, fmaxf(fmaxf(fabsf(v.x), fabsf(v.y)), fmaxf(fabsf(v.z), fabsf(v.w))));
    }
    float r = bmax256(m, red);
    if (t == 0) ((float*)(ws + OFF_PMAX))[blockIdx.x] = r;
}

// quantize x -> xq packed codes; conv1 max-scan (sdot4) with wave ANY-exit
__global__ __launch_bounds__(256) void kmax1q(const float* __restrict__ x,
                                              unsigned char* __restrict__ ws)
{
    __shared__ unsigned s_w1p[CMID*8];
    __shared__ float s_bn1[576];
    __shared__ float red[256];
    const int t = threadIdx.x;

    {
        const uint4* src = (const uint4*)(ws + OFF_W1P);
        uint4* dst = (uint4*)s_w1p;
        for (int i = t; i < CMID*8/4; i += 256) dst[i] = src[i];
        const float* b = (const float*)(ws + OFF_BN1);
        for (int i = t; i < 576; i += 256) s_bn1[i] = b[i];
    }

    const float* wsc = (const float*)(ws + OFF_WSC);
    unsigned char* xq = ws + OFF_XQ;

    // self-reduce per-block partials -> sx (identical in every block)
    float pm = 0.f;
    const float* pmax = (const float*)(ws + OFF_PMAX);
    for (int i = t; i < 2048; i += 256) pm = fmaxf(pm, pmax[i]);
    float sxr = bmax256(pm, red);
    if (blockIdx.x == 0 && t == 0) ((unsigned*)(ws + OFF_SCAL))[0] = __float_as_uint(sxr);
    const float sx = sxr + 1e-8f;
    const float C1 = (float)(((double)sx / 7.0) * ((double)wsc[0] / 7.0));

    const int p = blockIdx.x * 256 + t;
    const int n = p / HW, pi = p % HW;
    const float* xp = x + (size_t)n * CIN * HW + pi;

    float kx[CIN];
#pragma unroll
    for (int ic = 0; ic < CIN; ++ic) {
        float v = xp[(size_t)ic * HW] / sx;
        v = fminf(fmaxf(v, -1.f), 1.f);
        kx[ic] = rintf(__fmul_rn(v, 7.f));
    }

    unsigned wb[8];
#pragma unroll
    for (int j = 0; j < 8; ++j) {
        unsigned b0 = (unsigned)(int)kx[4*j]     & 0xffu;
        unsigned b1 = (unsigned)(int)kx[4*j + 1] & 0xffu;
        unsigned b2 = (unsigned)(int)kx[4*j + 2] & 0xffu;
        unsigned b3 = (unsigned)(int)kx[4*j + 3] & 0xffu;
        wb[j] = b0 | (b1 << 8) | (b2 << 16) | (b3 << 24);
    }
    uint4* q4 = (uint4*)(xq + (size_t)p * 32);
    q4[0] = make_uint4(wb[0], wb[1], wb[2], wb[3]);
    q4[1] = make_uint4(wb[4], wb[5], wb[6], wb[7]);

    __syncthreads();

    float mx = 0.f;
    for (int oc = 0; oc < CMID; ++oc) {
        int d = 0;
#pragma unroll
        for (int j = 0; j < 8; ++j) d = sdot4(wb[j], s_w1p[oc*8 + j], d);
        float h = bnq((float)d, C1, s_bn1[192+oc], s_bn1[oc], s_bn1[384+oc]);
        mx = fmaxf(mx, h);
        if (__any(mx >= 6.0f)) break;    // any lane capped -> wave max settled (=6)
    }
    float r = bmax256(mx, red);
    if (t == 0) atomicMax((unsigned*)(ws + OFF_SCAL) + 1, __float_as_uint(r));
}

// per-channel fast-quant coefficients + EXHAUSTIVE verification
__global__ __launch_bounds__(64) void kcoef(unsigned char* __restrict__ ws, int stage)
{
    const unsigned* scal = (const unsigned*)(ws + OFF_SCAL);
    const float* wsc = (const float*)(ws + OFF_WSC);
    const int c = blockIdx.x, lane = threadIdx.x;
    const float* bn = (const float*)(ws + (stage == 1 ? OFF_BN1 : OFF_BN2));
    float* fq = (float*)(ws + (stage == 1 ? OFF_FQ1 : OFF_FQ2));

    float C, s; int R;
    if (stage == 1) {
        float sx = __uint_as_float(scal[0]) + 1e-8f;
        C = (float)(((double)sx / 7.0) * ((double)wsc[0] / 7.0));
        s = __uint_as_float(scal[1]) + 1e-8f;
        R = 1568;
    } else {
        float s1 = __uint_as_float(scal[1]) + 1e-8f;
        C = (float)(((double)s1 / 15.0) * ((double)wsc[1] / 7.0));
        s = __uint_as_float(scal[2]) + 1e-8f;
        R = 945;
    }
    const float gi = bn[c], mm = bn[192+c], bb = bn[384+c];
    const float A = (float)((double)C * (double)gi * 15.0 / (double)s);
    const float B = (float)(((double)bb - (double)mm * (double)gi) * 15.0 / (double)s);

    bool bad = false;
    for (int d = -R + lane; d <= R; d += 64) {
        float df = (float)d;
        float je = qexact15(bnq(df, C, mm, gi, bb), s);
        float jf = qfast15(df, A, B);
        if (je != jf) bad = true;
    }
    bool any = __any(bad);
    if (lane == 0) {
        unsigned flagv = any ? 0u : 1u;
        fq[c] = A; fq[192+c] = B;
        ((unsigned*)fq)[384+c] = flagv;
        atomicAnd(((unsigned*)fq) + 576, flagv);
    }
}

// tile 14x14 out, halo 16x16 = 256 = blockDim; conv1(sdot4)+dw max(h2) scan
// with block ANY-hit early exit (cap 6). (usually exits after 1 phase)
__global__ __launch_bounds__(256) void kmax2(unsigned char* __restrict__ ws)
{
    __shared__ unsigned s_w1p[CMID*8];
    __shared__ float s_wdw[CMID*9];
    __shared__ float s_bn2[576];
    __shared__ unsigned s_fq1[576];
    __shared__ float jl[8][256];
    __shared__ float red[256];
    __shared__ unsigned s_flag;
    const int t = threadIdx.x;

    {
        const uint4* sp = (const uint4*)(ws + OFF_W1P);
        uint4* dp = (uint4*)s_w1p;
        for (int i = t; i < CMID*8/4; i += 256) dp[i] = sp[i];
        const float* wp = (const float*)(ws + OFF_WDW);
        for (int i = t; i < CMID*9; i += 256) s_wdw[i] = wp[i];
        const float* b2p = (const float*)(ws + OFF_BN2);
        for (int i = t; i < 576; i += 256) s_bn2[i] = b2p[i];
        const unsigned* fp = (const unsigned*)(ws + OFF_FQ1);
        for (int i = t; i < 576; i += 256) s_fq1[i] = fp[i];
        if (t == 0) s_flag = 0u;
    }

    const unsigned* scal = (const unsigned*)(ws + OFF_SCAL);
    const float* wsc = (const float*)(ws + OFF_WSC);
    const float* gbn1 = (const float*)(ws + OFF_BN1);
    const unsigned char* xq = ws + OFF_XQ;

    const float sx  = __uint_as_float(scal[0]) + 1e-8f;
    const float s1v = __uint_as_float(scal[1]) + 1e-8f;
    const float C1  = (float)(((double)sx  / 7.0)  * ((double)wsc[0] / 7.0));
    const float C2  = (float)(((double)s1v / 15.0) * ((double)wsc[1] / 7.0));

    const int tile = blockIdx.x, n = blockIdx.y;
    const int ty = t >> 4, tx = t & 15;
    const int hy = (tile >> 3) * 14 - 1 + ty;
    const int wx = (tile & 7)  * 14 - 1 + tx;
    const bool inb = (hy >= 0 && hy < WID && wx >= 0 && wx < WID);
    const bool act = (ty < 14) && (tx < 14);

    unsigned wb[8];
    if (inb) {
        const uint4* q4 = (const uint4*)(xq + ((size_t)n * HW + hy * WID + wx) * 32);
        uint4 a = q4[0], b4 = q4[1];
        wb[0]=a.x; wb[1]=a.y; wb[2]=a.z; wb[3]=a.w;
        wb[4]=b4.x; wb[5]=b4.y; wb[6]=b4.z; wb[7]=b4.w;
    } else {
#pragma unroll
        for (int j = 0; j < 8; ++j) wb[j] = 0u;
    }
    __syncthreads();

    float mx = 0.f;
    for (int ph = 0; ph < CMID/8; ++ph) {
#pragma unroll
        for (int k = 0; k < 8; ++k) {
            const int c = ph*8 + k;
            int d1 = 0;
#pragma unroll
            for (int j = 0; j < 8; ++j) d1 = sdot4(wb[j], s_w1p[c*8 + j], d1);
            float j1 = 0.f;
            if (inb) {
                float d1f = (float)d1;
                if (s_fq1[384+c]) {
                    j1 = qfast15(d1f, __uint_as_float(s_fq1[c]), __uint_as_float(s_fq1[192+c]));
                } else {
                    float h1 = bnq(d1f, C1, gbn1[192+c], gbn1[c], gbn1[384+c]);
                    j1 = qexact15(h1, s1v);
                }
            }
            jl[k][t] = j1;
        }
        __syncthreads();
        if (act) {
#pragma unroll
            for (int k = 0; k < 8; ++k) {
                const int c = ph*8 + k;
                const float* wd = s_wdw + c * 9;
                float d2 = 0.f;
#pragma unroll
                for (int dy = 0; dy < 3; ++dy)
#pragma unroll
                    for (int dx = 0; dx < 3; ++dx)
                        d2 = fmaf(jl[k][(ty+dy)*16 + tx+dx], wd[dy*3+dx], d2);
                float h2 = bnq(d2, C2, s_bn2[192+c], s_bn2[c], s_bn2[384+c]);
                mx = fmaxf(mx, h2);
            }
        }
        if (mx >= 6.0f) s_flag = 1u;
        __syncthreads();
        if (s_flag) break;
    }
    float r = bmax256(mx, red);
    if (t == 0) atomicMax((unsigned*)(ws + OFF_SCAL) + 2, __float_as_uint(r));
}

// full chain with MFMA: conv1 MFMA -> j1 quad float4 -> dw -> j2 bytes -> conv2 MFMA
__global__ __launch_bounds__(256) void kconv2(unsigned char* __restrict__ ws,
                                              float* __restrict__ h3)
{
    __shared__ ull   s_w1a[12*64];
    __shared__ ull   s_w2a[2*6*64];
    __shared__ float4 s_wdwT[48*9];
    __shared__ float s_fqA1[192], s_fqB1[192], s_fqA2[192], s_fqB2[192];
    __shared__ float s_bn1[576], s_bn2[576], s_bn3[96];
    __shared__ float4 jl4[4][256];          // [oc-quad][halo pixel]
    __shared__ unsigned j2buf[256][8];      // [pixel][32B = 2-phase j2 bytes]
    __shared__ float red[256];
    __shared__ int s_af1, s_af2;
    const int t = threadIdx.x;

    {
        const uint4* a = (const uint4*)(ws + OFF_W1A);
        uint4* da = (uint4*)s_w1a;
        for (int i = t; i < 384; i += 256) da[i] = a[i];
        const uint4* b = (const uint4*)(ws + OFF_W2A);
        uint4* db = (uint4*)s_w2a;
        for (int i = t; i < 384; i += 256) db[i] = b[i];
        const uint4* c = (const uint4*)(ws + OFF_WDWT);
        uint4* dc = (uint4*)s_wdwT;
        for (int i = t; i < 432; i += 256) dc[i] = c[i];
        const float* f1 = (const float*)(ws + OFF_FQ1);
        const float* f2 = (const float*)(ws + OFF_FQ2);
        for (int i = t; i < 192; i += 256) {
            s_fqA1[i] = f1[i]; s_fqB1[i] = f1[192+i];
            s_fqA2[i] = f2[i]; s_fqB2[i] = f2[192+i];
        }
        const float* b1p = (const float*)(ws + OFF_BN1);
        const float* b2p = (const float*)(ws + OFF_BN2);
        for (int i = t; i < 576; i += 256) { s_bn1[i] = b1p[i]; s_bn2[i] = b2p[i]; }
        const float* b3p = (const float*)(ws + OFF_BN3);
        if (t < 96) s_bn3[t] = b3p[t];
        if (t == 0) {
            s_af1 = (int)((const unsigned*)(ws + OFF_FQ1))[576];
            s_af2 = (int)((const unsigned*)(ws + OFF_FQ2))[576];
        }
    }

    const unsigned* scal = (const unsigned*)(ws + OFF_SCAL);
    const float* wsc = (const float*)(ws + OFF_WSC);
    const unsigned char* xq = ws + OFF_XQ;

    const float sx  = __uint_as_float(scal[0]) + 1e-8f;
    const float s1v = __uint_as_float(scal[1]) + 1e-8f;
    const float s2v = __uint_as_float(scal[2]) + 1e-8f;
    const float C1  = (float)(((double)sx  / 7.0)  * ((double)wsc[0] / 7.0));
    const float C2  = (float)(((double)s1v / 15.0) * ((double)wsc[1] / 7.0));
    const float C3  = (float)(((double)s2v / 15.0) * ((double)wsc[2] / 7.0));

    const int tile = blockIdx.x, n = blockIdx.y;
    const int y0 = (tile >> 3) * 14, x0 = (tile & 7) * 14;
    const int lane = t & 63, wid = t >> 6;
    const int ty = t >> 4, tx = t & 15;
    const bool act = (ty < 14) && (tx < 14);
    const int px = lane & 15, kq = lane >> 4;   // pixel col / k-chunk of this lane

    // conv1 B-fragments: group g = 4*wid+i, pixel = g*16 + px, 8 bytes at kq*8
    ull  xb[4];
    bool okb[4];
#pragma unroll
    for (int i = 0; i < 4; ++i) {
        int g = 4*wid + i;
        int bhy = y0 - 1 + g, bwx = x0 - 1 + px;
        bool ok = (bhy >= 0) && (bhy < WID) && (bwx >= 0) && (bwx < WID);
        okb[i] = ok;
        ull v = 0;
        if (ok) v = *(const ull*)(xq + (((size_t)n * HW + bhy * WID + bwx) * 32 + kq * 8));
        xb[i] = v;
    }
    __syncthreads();   // staging complete

    v4i acc2[2][4];
#pragma unroll
    for (int o = 0; o < 2; ++o)
#pragma unroll
        for (int i = 0; i < 4; ++i) { acc2[o][i][0]=0; acc2[o][i][1]=0; acc2[o][i][2]=0; acc2[o][i][3]=0; }

    for (int ph = 0; ph < 12; ++ph) {
        // ---- conv1 MFMA: 16 oc (octile=ph) x 64 pixels per wave ----
        ull a1 = s_w1a[ph*64 + lane];
        const int oc0 = ph*16 + kq*4;
        float4 A14, B14;
        A14 = *(const float4*)&s_fqA1[oc0];
        B14 = *(const float4*)&s_fqB1[oc0];
#pragma unroll
        for (int i = 0; i < 4; ++i) {
            v4i z = {0,0,0,0};
            v4i d = mfma_i8(a1, xb[i], z);
            float4 j1v;
            if (s_af1) {
                j1v.x = okb[i] ? qfast15((float)d[0], A14.x, B14.x) : 0.f;
                j1v.y = okb[i] ? qfast15((float)d[1], A14.y, B14.y) : 0.f;
                j1v.z = okb[i] ? qfast15((float)d[2], A14.z, B14.z) : 0.f;
                j1v.w = okb[i] ? qfast15((float)d[3], A14.w, B14.w) : 0.f;
            } else {
                float jj[4];
#pragma unroll
                for (int r = 0; r < 4; ++r) {
                    int oc = oc0 + r;
                    float h1 = bnq((float)d[r], C1, s_bn1[192+oc], s_bn1[oc], s_bn1[384+oc]);
                    jj[r] = okb[i] ? qexact15(h1, s1v) : 0.f;
                }
                j1v.x = jj[0]; j1v.y = jj[1]; j1v.z = jj[2]; j1v.w = jj[3];
            }
            jl4[kq][(4*wid + i)*16 + px] = j1v;
        }
        __syncthreads();   // jl4 ready

        // ---- dw on float4 quads + j2 pack ----
        unsigned pw0 = 0, pw1 = 0, pw2 = 0, pw3 = 0;
        if (act) {
            unsigned pw[4];
#pragma unroll
            for (int q = 0; q < 4; ++q) {
                float4 s = {0.f, 0.f, 0.f, 0.f};
#pragma unroll
                for (int dy = 0; dy < 3; ++dy)
#pragma unroll
                    for (int dx = 0; dx < 3; ++dx) {
                        float4 wv = s_wdwT[(ph*4 + q)*9 + dy*3 + dx];
                        float4 jv = jl4[q][(ty+dy)*16 + tx+dx];
                        s.x = fmaf(jv.x, wv.x, s.x);
                        s.y = fmaf(jv.y, wv.y, s.y);
                        s.z = fmaf(jv.z, wv.z, s.z);
                        s.w = fmaf(jv.w, wv.w, s.w);
                    }
                const int oc2 = ph*16 + q*4;
                float j2a, j2b, j2c, j2d;
                if (s_af2) {
                    float4 A24 = *(const float4*)&s_fqA2[oc2];
                    float4 B24 = *(const float4*)&s_fqB2[oc2];
                    j2a = qfast15(s.x, A24.x, B24.x);
                    j2b = qfast15(s.y, A24.y, B24.y);
                    j2c = qfast15(s.z, A24.z, B24.z);
                    j2d = qfast15(s.w, A24.w, B24.w);
                } else {
                    j2a = qexact15(bnq(s.x, C2, s_bn2[192+oc2],   s_bn2[oc2],   s_bn2[384+oc2]),   s2v);
                    j2b = qexact15(bnq(s.y, C2, s_bn2[192+oc2+1], s_bn2[oc2+1], s_bn2[384+oc2+1]), s2v);
                    j2c = qexact15(bnq(s.z, C2, s_bn2[192+oc2+2], s_bn2[oc2+2], s_bn2[384+oc2+2]), s2v);
                    j2d = qexact15(bnq(s.w, C2, s_bn2[192+oc2+3], s_bn2[oc2+3], s_bn2[384+oc2+3]), s2v);
                }
                pw[q] = ((unsigned)(int)j2a) | ((unsigned)(int)j2b << 8) |
                        ((unsigned)(int)j2c << 16) | ((unsigned)(int)j2d << 24);
            }
            pw0 = pw[0]; pw1 = pw[1]; pw2 = pw[2]; pw3 = pw[3];
        }
        *(uint4*)&j2buf[t][(ph & 1) * 4] = make_uint4(pw0, pw1, pw2, pw3);

        if (ph & 1) {
            __syncthreads();   // j2buf ready (32 channels)
            const int chunk = ph >> 1;
#pragma unroll
            for (int oct = 0; oct < 2; ++oct) {
                ull a2 = s_w2a[(oct*6 + chunk)*64 + lane];
#pragma unroll
                for (int i = 0; i < 4; ++i) {
                    int g = 4*wid + i;
                    ull b2 = *(const ull*)&j2buf[g*16 + px][kq * 2];
                    acc2[oct][i] = mfma_i8(a2, b2, acc2[oct][i]);
                }
            }
        }
        __syncthreads();       // protect jl4 (+ j2buf after conv2) for next phase
    }

    // ---- bn3 + store h3 + max|h3| ----
    float mx = 0.f;
#pragma unroll
    for (int oct = 0; oct < 2; ++oct)
#pragma unroll
        for (int i = 0; i < 4; ++i) {
            int g = 4*wid + i;
            if (g < 14 && px < 14) {
                int gy = y0 + g, gx = x0 + px;
#pragma unroll
                for (int r = 0; r < 4; ++r) {
                    int oc = oct*16 + kq*4 + r;
                    float y = __fmul_rn((float)acc2[oct][i][r], C3);
                    float h = __fadd_rn(__fmul_rn(__fsub_rn(y, s_bn3[32+oc]), s_bn3[oc]), s_bn3[64+oc]);
                    h3[((size_t)n * COUT + oc) * HW + gy * WID + gx] = h;
                    mx = fmaxf(mx, fabsf(h));
                }
            }
        }
    float r = bmax256(mx, red);
    if (t == 0) atomicMax((unsigned*)(ws + OFF_SCAL) + 3, __float_as_uint(r));
}

// in-place on d_out: out = x + actq_signed(h3)
__global__ __launch_bounds__(256) void kout(const float4* __restrict__ x4,
                                            float4* __restrict__ io4,
                                            const unsigned char* __restrict__ ws)
{
    const unsigned* scal = (const unsigned*)(ws + OFF_SCAL);
    const float s3v = __uint_as_float(scal[3]) + 1e-8f;

    for (size_t i = (size_t)blockIdx.x*256 + threadIdx.x; i < NX/4; i += (size_t)gridDim.x*256) {
        float4 h = io4[i], xv = x4[i], o;
        float* hp = &h.x; float* xp = &xv.x; float* op = &o.x;
#pragma unroll
        for (int k = 0; k < 4; ++k) {
            float tq = fminf(fmaxf(hp[k] / s3v, -1.f), 1.f);
            float kq = rintf(__fmul_rn(tq, 7.f));
            float q  = __fmul_rn(kq / 7.f, s3v);
            op[k] = __fadd_rn(xp[k], q);
        }
        io4[i] = o;
    }
}

extern "C" void kernel_launch(void* const* d_in, const int* in_sizes, int n_in,
                              void* d_out, int out_size, void* d_ws, size_t ws_size,
                              hipStream_t stream)
{
    const float* x   = (const float*)d_in[0];
    const float* w1  = (const float*)d_in[1];
    const float* g1  = (const float*)d_in[2];
    const float* b1  = (const float*)d_in[3];
    const float* m1  = (const float*)d_in[4];
    const float* v1  = (const float*)d_in[5];
    const float* wdw = (const float*)d_in[6];
    const float* g2  = (const float*)d_in[7];
    const float* b2  = (const float*)d_in[8];
    const float* m2  = (const float*)d_in[9];
    const float* v2  = (const float*)d_in[10];
    const float* w2  = (const float*)d_in[11];
    const float* g3  = (const float*)d_in[12];
    const float* b3  = (const float*)d_in[13];
    const float* m3  = (const float*)d_in[14];
    const float* v3  = (const float*)d_in[15];
    unsigned char* ws = (unsigned char*)d_ws;

    hipLaunchKernelGGL(kprepx, dim3(2048), dim3(256), 0, stream, (const float4*)x,
                       w1, wdw, w2, g1, b1, m1, v1, g2, b2, m2, v2, g3, b3, m3, v3, ws);
    hipLaunchKernelGGL(kmax1q, dim3(NPIX/256), dim3(256), 0, stream, x, ws);
    hipLaunchKernelGGL(kcoef, dim3(CMID), dim3(64), 0, stream, ws, 1);
    hipLaunchKernelGGL(kmax2, dim3(64, NB), dim3(256), 0, stream, ws);
    hipLaunchKernelGGL(kcoef, dim3(CMID), dim3(64), 0, stream, ws, 2);
    hipLaunchKernelGGL(kconv2, dim3(64, NB), dim3(256), 0, stream, ws, (float*)d_out);
    hipLaunchKernelGGL(kout, dim3(2048), dim3(256), 0, stream,
                       (const float4*)x, (float4*)d_out, ws);
}

// Round 8
// 257.172 us; speedup vs baseline: 3.7943x; 1.0860x over previous
//
#include <hip/hip_runtime.h>

// InvertedResidualQ on MI355X. Exact-integer quantized-conv formulation.
// R8 = R7 with compile fix (cvt_pkrtz returns __fp16x2 -> bitcast to h2).
// Depthwise on packed f16 (exact: j1<=15, |w|<=7, |d2|<=945 < 2048 so all f16
// products/sums are exact integers); padded jl rows + 9-word j2buf rows kill
// LDS bank conflicts; 2 barriers/phase. Quant chains kcoef-verified.

#define HW    12544      // 112*112
#define WID   112
#define CIN   32
#define CMID  192
#define COUT  32
#define NB    32
#define NPIX  (NB*HW)        // 401408
#define NX    (NB*CIN*HW)    // 12845056

// workspace layout (bytes)
#define OFF_SCAL   0         // 4 u32: [0]=sx (plain store), 1..3 atomic-max s1,s2,s3
#define OFF_WSC    16        // 3 f32 weight scales
#define OFF_BN1    64        // gi[192], m[192], b[192]
#define OFF_BN2    2368
#define OFF_BN3    4672      // gi[32], m[32], b[32] (384B)
#define OFF_FQ1    5120      // A[192],B[192] f32, flag[192] u32, allfast u32
#define OFF_FQ2    7488
#define OFF_W1P    9856      // 192*8 u32 packed i8 conv1 weights (sdot4 path)
#define OFF_WDW    16000     // 192*9 f32 dw codes (kmax2)
#define OFF_W1A    22912     // 12*64*8B conv1 A-fragments
#define OFF_W2A    29056     // 2*6*64*8B conv2 A-fragments
#define OFF_WDWH   35200     // 48*9 uint2 (4x f16 dw codes per quad-tap)
#define OFF_PMAX   42112     // 2048 f32 per-block |x| partial maxes
#define OFF_XQ     65536     // NPIX*32 i8 packed input codes, [pix][ic]

#define PADP(p) ((p) + ((p) >> 4))   // 16->17 row stride: kills LDS row aliasing

typedef int v4i __attribute__((ext_vector_type(4)));
typedef unsigned long long ull;
typedef _Float16 h2 __attribute__((ext_vector_type(2)));

__device__ __forceinline__ unsigned h2u(h2 v){ union{h2 h; unsigned u;} c; c.h=v; return c.u; }
__device__ __forceinline__ h2 u2h(unsigned u){ union{h2 h; unsigned u;} c; c.u=u; return c.h; }
__device__ __forceinline__ h2 pkrtz(float a, float b){
    auto r = __builtin_amdgcn_cvt_pkrtz(a, b);      // __fp16x2
    union { decltype(r) f; h2 h; } c; c.f = r; return c.h;
}

#if defined(__has_builtin)
#if __has_builtin(__builtin_amdgcn_sdot4)
#define HAVE_SDOT4 1
#endif
#endif

__device__ __forceinline__ int sdot4(unsigned a, unsigned b, int c) {
#ifdef HAVE_SDOT4
    return __builtin_amdgcn_sdot4((int)a, (int)b, c, false);
#else
    c += (int)(signed char)(a & 0xff)        * (int)(signed char)(b & 0xff);
    c += (int)(signed char)((a >> 8) & 0xff) * (int)(signed char)((b >> 8) & 0xff);
    c += (int)(signed char)((a >> 16) & 0xff)* (int)(signed char)((b >> 16) & 0xff);
    c += (int)(signed char)(a >> 24)         * (int)(signed char)(b >> 24);
    return c;
#endif
}

__device__ __forceinline__ v4i mfma_i8(ull a, ull b, v4i c) {
    return __builtin_amdgcn_mfma_i32_16x16x32_i8((long)a, (long)b, c, 0, 0, 0);
}

__device__ __forceinline__ float bmax256(float v, float* red) {
    const int t = threadIdx.x;
    red[t] = v; __syncthreads();
    for (int s = 128; s; s >>= 1) {
        if (t < s) red[t] = fmaxf(red[t], red[t + s]);
        __syncthreads();
    }
    float r = red[0]; __syncthreads();
    return r;
}

__device__ __forceinline__ float qcode(float x, float s, float n, float lo) {
    float t = x / s;
    t = fminf(fmaxf(t, lo), 1.0f);
    return rintf(__fmul_rn(t, n));
}

__device__ __forceinline__ float bnq(float d, float C, float m, float g, float b) {
    float y = __fmul_rn(d, C);
    float h = __fadd_rn(__fmul_rn(__fsub_rn(y, m), g), b);
    return fminf(fmaxf(h, 0.f), 6.f);
}

__device__ __forceinline__ float qexact15(float h, float s) {
    return rintf(__fmul_rn(fminf(h / s, 1.f), 15.f));
}
__device__ __forceinline__ float qfast15(float df, float A, float B) {
    float t = fmaf(df, A, B);
    return rintf(fminf(fmaxf(t, 0.f), 15.f));
}

// merged prep (block 0) + |x| partial max (all blocks -> pmax[block])
__global__ __launch_bounds__(256) void kprepx(
    const float4* __restrict__ x4,
    const float* __restrict__ w1, const float* __restrict__ wdw, const float* __restrict__ w2,
    const float* __restrict__ g1, const float* __restrict__ b1, const float* __restrict__ m1, const float* __restrict__ v1,
    const float* __restrict__ g2, const float* __restrict__ b2, const float* __restrict__ m2, const float* __restrict__ v2,
    const float* __restrict__ g3, const float* __restrict__ b3, const float* __restrict__ m3, const float* __restrict__ v3,
    unsigned char* __restrict__ ws)
{
    __shared__ float red[256];
    const int t = threadIdx.x;

    if (blockIdx.x == 0) {
        unsigned* scal = (unsigned*)(ws + OFF_SCAL);
        float* wsc  = (float*)(ws + OFF_WSC);
        float* bn1  = (float*)(ws + OFF_BN1);
        float* bn2  = (float*)(ws + OFF_BN2);
        float* bn3  = (float*)(ws + OFF_BN3);
        unsigned* w1p = (unsigned*)(ws + OFF_W1P);
        float*  wdwf  = (float*)(ws + OFF_WDW);

        if (t < 4) scal[t] = 0u;
        if (t == 0) { ((unsigned*)(ws+OFF_FQ1))[576] = 1u; ((unsigned*)(ws+OFF_FQ2))[576] = 1u; }

        float m;
        m = 0.f; for (int i = t; i < CMID*CIN; i += 256) m = fmaxf(m, fabsf(w1[i]));
        float sw1 = bmax256(m, red) + 1e-8f;
        m = 0.f; for (int i = t; i < CMID*9; i += 256) m = fmaxf(m, fabsf(wdw[i]));
        float swd = bmax256(m, red) + 1e-8f;
        m = 0.f; for (int i = t; i < COUT*CMID; i += 256) m = fmaxf(m, fabsf(w2[i]));
        float sw2 = bmax256(m, red) + 1e-8f;
        if (t == 0) { wsc[0] = sw1; wsc[1] = swd; wsc[2] = sw2; }

        // packed i8 conv1 weights (sdot4 path, kmax1q/kmax2)
        for (int i = t; i < CMID*8; i += 256) {
            int oc = i >> 3, j = i & 7;
            unsigned wword = 0;
#pragma unroll
            for (int k = 0; k < 4; ++k) {
                int code = (int)qcode(w1[oc*CIN + 4*j + k], sw1, 7.f, -1.f);
                wword |= ((unsigned)code & 0xffu) << (8*k);
            }
            w1p[i] = wword;
        }
        for (int i = t; i < CMID*9; i += 256) wdwf[i] = qcode(wdw[i], swd, 7.f, -1.f);

        // conv1 A-fragments: [octile][lane] 8B, oc = octile*16+(l&15), ic = (l>>4)*8+e
        for (int i = t; i < 12*64; i += 256) {
            int octile = i >> 6, l = i & 63;
            int oc = octile*16 + (l & 15), icb = (l >> 4) * 8;
            unsigned lo = 0, hi = 0;
#pragma unroll
            for (int k = 0; k < 4; ++k) {
                lo |= ((unsigned)(int)qcode(w1[oc*CIN + icb + k],     sw1, 7.f, -1.f) & 0xffu) << (8*k);
                hi |= ((unsigned)(int)qcode(w1[oc*CIN + icb + 4 + k], sw1, 7.f, -1.f) & 0xffu) << (8*k);
            }
            ((unsigned*)(ws + OFF_W1A))[i*2]   = lo;
            ((unsigned*)(ws + OFF_W1A))[i*2+1] = hi;
        }
        // conv2 A-fragments: [oct][chunk][lane] 8B, oc = oct*16+(l&15), ch = chunk*32+(l>>4)*8+e
        for (int i = t; i < 2*6*64; i += 256) {
            int oct = i / 384, rem = i % 384, chunk = rem >> 6, l = rem & 63;
            int oc = oct*16 + (l & 15), cb = chunk*32 + (l >> 4) * 8;
            unsigned lo = 0, hi = 0;
#pragma unroll
            for (int k = 0; k < 4; ++k) {
                lo |= ((unsigned)(int)qcode(w2[oc*CMID + cb + k],     sw2, 7.f, -1.f) & 0xffu) << (8*k);
                hi |= ((unsigned)(int)qcode(w2[oc*CMID + cb + 4 + k], sw2, 7.f, -1.f) & 0xffu) << (8*k);
            }
            ((unsigned*)(ws + OFF_W2A))[i*2]   = lo;
            ((unsigned*)(ws + OFF_W2A))[i*2+1] = hi;
        }
        // dw weights as packed f16 quad pairs: [qg][tap] -> 2x half2 (exact ints)
        for (int i = t; i < 48*9; i += 256) {
            int qg = i / 9, tap = i % 9;
            float c0 = qcode(wdw[(qg*4+0)*9 + tap], swd, 7.f, -1.f);
            float c1 = qcode(wdw[(qg*4+1)*9 + tap], swd, 7.f, -1.f);
            float c2 = qcode(wdw[(qg*4+2)*9 + tap], swd, 7.f, -1.f);
            float c3 = qcode(wdw[(qg*4+3)*9 + tap], swd, 7.f, -1.f);
            ((uint2*)(ws + OFF_WDWH))[i] = make_uint2(h2u(pkrtz(c0, c1)), h2u(pkrtz(c2, c3)));
        }

        for (int c = t; c < CMID; c += 256) {
            float vv1 = v1[c] + 1e-5f;
            bn1[c] = __fmul_rn(g1[c], (float)(1.0 / sqrt((double)vv1)));
            bn1[192+c] = m1[c]; bn1[384+c] = b1[c];
            float vv2 = v2[c] + 1e-5f;
            bn2[c] = __fmul_rn(g2[c], (float)(1.0 / sqrt((double)vv2)));
            bn2[192+c] = m2[c]; bn2[384+c] = b2[c];
        }
        for (int c = t; c < COUT; c += 256) {
            float vv3 = v3[c] + 1e-5f;
            bn3[c] = __fmul_rn(g3[c], (float)(1.0 / sqrt((double)vv3)));
            bn3[32+c] = m3[c]; bn3[64+c] = b3[c];
        }
    }

    // |x| partial max -> pmax[blockIdx.x] (plain store, no reset race)
    float m = 0.f;
    for (size_t i = (size_t)blockIdx.x*256 + t; i < NX/4; i += (size_t)gridDim.x*256) {
        float4 v = x4[i];
        m = fmaxf(m, fmaxf(fmaxf(fabsf(v.x), fabsf(v.y)), fmaxf(fabsf(v.z), fabsf(v.w))));
    }
    float r = bmax256(m, red);
    if (t == 0) ((float*)(ws + OFF_PMAX))[blockIdx.x] = r;
}

// quantize x -> xq packed codes; conv1 max-scan (sdot4) with wave ANY-exit
__global__ __launch_bounds__(256) void kmax1q(const float* __restrict__ x,
                                              unsigned char* __restrict__ ws)
{
    __shared__ unsigned s_w1p[CMID*8];
    __shared__ float s_bn1[576];
    __shared__ float red[256];
    const int t = threadIdx.x;

    {
        const uint4* src = (const uint4*)(ws + OFF_W1P);
        uint4* dst = (uint4*)s_w1p;
        for (int i = t; i < CMID*8/4; i += 256) dst[i] = src[i];
        const float* b = (const float*)(ws + OFF_BN1);
        for (int i = t; i < 576; i += 256) s_bn1[i] = b[i];
    }

    const float* wsc = (const float*)(ws + OFF_WSC);
    unsigned char* xq = ws + OFF_XQ;

    // self-reduce per-block partials -> sx (identical in every block)
    float pm = 0.f;
    const float* pmax = (const float*)(ws + OFF_PMAX);
    for (int i = t; i < 2048; i += 256) pm = fmaxf(pm, pmax[i]);
    float sxr = bmax256(pm, red);
    if (blockIdx.x == 0 && t == 0) ((unsigned*)(ws + OFF_SCAL))[0] = __float_as_uint(sxr);
    const float sx = sxr + 1e-8f;
    const float C1 = (float)(((double)sx / 7.0) * ((double)wsc[0] / 7.0));

    const int p = blockIdx.x * 256 + t;
    const int n = p / HW, pi = p % HW;
    const float* xp = x + (size_t)n * CIN * HW + pi;

    float kx[CIN];
#pragma unroll
    for (int ic = 0; ic < CIN; ++ic) {
        float v = xp[(size_t)ic * HW] / sx;
        v = fminf(fmaxf(v, -1.f), 1.f);
        kx[ic] = rintf(__fmul_rn(v, 7.f));
    }

    unsigned wb[8];
#pragma unroll
    for (int j = 0; j < 8; ++j) {
        unsigned b0 = (unsigned)(int)kx[4*j]     & 0xffu;
        unsigned b1 = (unsigned)(int)kx[4*j + 1] & 0xffu;
        unsigned b2 = (unsigned)(int)kx[4*j + 2] & 0xffu;
        unsigned b3 = (unsigned)(int)kx[4*j + 3] & 0xffu;
        wb[j] = b0 | (b1 << 8) | (b2 << 16) | (b3 << 24);
    }
    uint4* q4 = (uint4*)(xq + (size_t)p * 32);
    q4[0] = make_uint4(wb[0], wb[1], wb[2], wb[3]);
    q4[1] = make_uint4(wb[4], wb[5], wb[6], wb[7]);

    __syncthreads();

    float mx = 0.f;
    for (int oc = 0; oc < CMID; ++oc) {
        int d = 0;
#pragma unroll
        for (int j = 0; j < 8; ++j) d = sdot4(wb[j], s_w1p[oc*8 + j], d);
        float h = bnq((float)d, C1, s_bn1[192+oc], s_bn1[oc], s_bn1[384+oc]);
        mx = fmaxf(mx, h);
        if (__any(mx >= 6.0f)) break;    // any lane capped -> wave max settled (=6)
    }
    float r = bmax256(mx, red);
    if (t == 0) atomicMax((unsigned*)(ws + OFF_SCAL) + 1, __float_as_uint(r));
}

// per-channel fast-quant coefficients + EXHAUSTIVE verification
__global__ __launch_bounds__(64) void kcoef(unsigned char* __restrict__ ws, int stage)
{
    const unsigned* scal = (const unsigned*)(ws + OFF_SCAL);
    const float* wsc = (const float*)(ws + OFF_WSC);
    const int c = blockIdx.x, lane = threadIdx.x;
    const float* bn = (const float*)(ws + (stage == 1 ? OFF_BN1 : OFF_BN2));
    float* fq = (float*)(ws + (stage == 1 ? OFF_FQ1 : OFF_FQ2));

    float C, s; int R;
    if (stage == 1) {
        float sx = __uint_as_float(scal[0]) + 1e-8f;
        C = (float)(((double)sx / 7.0) * ((double)wsc[0] / 7.0));
        s = __uint_as_float(scal[1]) + 1e-8f;
        R = 1568;
    } else {
        float s1 = __uint_as_float(scal[1]) + 1e-8f;
        C = (float)(((double)s1 / 15.0) * ((double)wsc[1] / 7.0));
        s = __uint_as_float(scal[2]) + 1e-8f;
        R = 945;
    }
    const float gi = bn[c], mm = bn[192+c], bb = bn[384+c];
    const float A = (float)((double)C * (double)gi * 15.0 / (double)s);
    const float B = (float)(((double)bb - (double)mm * (double)gi) * 15.0 / (double)s);

    bool bad = false;
    for (int d = -R + lane; d <= R; d += 64) {
        float df = (float)d;
        float je = qexact15(bnq(df, C, mm, gi, bb), s);
        float jf = qfast15(df, A, B);
        if (je != jf) bad = true;
    }
    bool any = __any(bad);
    if (lane == 0) {
        unsigned flagv = any ? 0u : 1u;
        fq[c] = A; fq[192+c] = B;
        ((unsigned*)fq)[384+c] = flagv;
        atomicAnd(((unsigned*)fq) + 576, flagv);
    }
}

// tile 14x14 out, halo 16x16 = 256 = blockDim; conv1(sdot4)+dw max(h2) scan
// with block ANY-hit early exit (cap 6). (usually exits after 1 phase)
__global__ __launch_bounds__(256) void kmax2(unsigned char* __restrict__ ws)
{
    __shared__ unsigned s_w1p[CMID*8];
    __shared__ float s_wdw[CMID*9];
    __shared__ float s_bn2[576];
    __shared__ unsigned s_fq1[576];
    __shared__ float jl[8][256];
    __shared__ float red[256];
    __shared__ unsigned s_flag;
    const int t = threadIdx.x;

    {
        const uint4* sp = (const uint4*)(ws + OFF_W1P);
        uint4* dp = (uint4*)s_w1p;
        for (int i = t; i < CMID*8/4; i += 256) dp[i] = sp[i];
        const float* wp = (const float*)(ws + OFF_WDW);
        for (int i = t; i < CMID*9; i += 256) s_wdw[i] = wp[i];
        const float* b2p = (const float*)(ws + OFF_BN2);
        for (int i = t; i < 576; i += 256) s_bn2[i] = b2p[i];
        const unsigned* fp = (const unsigned*)(ws + OFF_FQ1);
        for (int i = t; i < 576; i += 256) s_fq1[i] = fp[i];
        if (t == 0) s_flag = 0u;
    }

    const unsigned* scal = (const unsigned*)(ws + OFF_SCAL);
    const float* wsc = (const float*)(ws + OFF_WSC);
    const float* gbn1 = (const float*)(ws + OFF_BN1);
    const unsigned char* xq = ws + OFF_XQ;

    const float sx  = __uint_as_float(scal[0]) + 1e-8f;
    const float s1v = __uint_as_float(scal[1]) + 1e-8f;
    const float C1  = (float)(((double)sx  / 7.0)  * ((double)wsc[0] / 7.0));
    const float C2  = (float)(((double)s1v / 15.0) * ((double)wsc[1] / 7.0));

    const int tile = blockIdx.x, n = blockIdx.y;
    const int ty = t >> 4, tx = t & 15;
    const int hy = (tile >> 3) * 14 - 1 + ty;
    const int wx = (tile & 7)  * 14 - 1 + tx;
    const bool inb = (hy >= 0 && hy < WID && wx >= 0 && wx < WID);
    const bool act = (ty < 14) && (tx < 14);

    unsigned wb[8];
    if (inb) {
        const uint4* q4 = (const uint4*)(xq + ((size_t)n * HW + hy * WID + wx) * 32);
        uint4 a = q4[0], b4 = q4[1];
        wb[0]=a.x; wb[1]=a.y; wb[2]=a.z; wb[3]=a.w;
        wb[4]=b4.x; wb[5]=b4.y; wb[6]=b4.z; wb[7]=b4.w;
    } else {
#pragma unroll
        for (int j = 0; j < 8; ++j) wb[j] = 0u;
    }
    __syncthreads();

    float mx = 0.f;
    for (int ph = 0; ph < CMID/8; ++ph) {
#pragma unroll
        for (int k = 0; k < 8; ++k) {
            const int c = ph*8 + k;
            int d1 = 0;
#pragma unroll
            for (int j = 0; j < 8; ++j) d1 = sdot4(wb[j], s_w1p[c*8 + j], d1);
            float j1 = 0.f;
            if (inb) {
                float d1f = (float)d1;
                if (s_fq1[384+c]) {
                    j1 = qfast15(d1f, __uint_as_float(s_fq1[c]), __uint_as_float(s_fq1[192+c]));
                } else {
                    float h1 = bnq(d1f, C1, gbn1[192+c], gbn1[c], gbn1[384+c]);
                    j1 = qexact15(h1, s1v);
                }
            }
            jl[k][t] = j1;
        }
        __syncthreads();
        if (act) {
#pragma unroll
            for (int k = 0; k < 8; ++k) {
                const int c = ph*8 + k;
                const float* wd = s_wdw + c * 9;
                float d2 = 0.f;
#pragma unroll
                for (int dy = 0; dy < 3; ++dy)
#pragma unroll
                    for (int dx = 0; dx < 3; ++dx)
                        d2 = fmaf(jl[k][(ty+dy)*16 + tx+dx], wd[dy*3+dx], d2);
                float h2 = bnq(d2, C2, s_bn2[192+c], s_bn2[c], s_bn2[384+c]);
                mx = fmaxf(mx, h2);
            }
        }
        if (mx >= 6.0f) s_flag = 1u;
        __syncthreads();
        if (s_flag) break;
    }
    float r = bmax256(mx, red);
    if (t == 0) atomicMax((unsigned*)(ws + OFF_SCAL) + 2, __float_as_uint(r));
}

// full chain with MFMA: conv1 MFMA -> j1 (f16 quads, padded LDS) -> dw (pk f16)
// -> j2 bytes (9-word rows) -> conv2 MFMA (after phase-end barrier)
__global__ __launch_bounds__(256) void kconv2(unsigned char* __restrict__ ws,
                                              float* __restrict__ h3)
{
    __shared__ ull   s_w1a[12*64];
    __shared__ ull   s_w2a[2*6*64];
    __shared__ uint2 s_wdwh[48*9];
    __shared__ float s_fqA1[192], s_fqB1[192], s_fqA2[192], s_fqB2[192];
    __shared__ float s_bn1[576], s_bn2[576], s_bn3[96];
    __shared__ uint2 jlh[4][272];           // [kq][padded pixel] 4x f16 channels
    __shared__ unsigned j2buf[256][9];      // 9-word rows: conflict-free
    __shared__ float red[256];
    __shared__ int s_af1, s_af2;
    const int t = threadIdx.x;

    {
        const uint4* a = (const uint4*)(ws + OFF_W1A);
        uint4* da = (uint4*)s_w1a;
        for (int i = t; i < 384; i += 256) da[i] = a[i];
        const uint4* b = (const uint4*)(ws + OFF_W2A);
        uint4* db = (uint4*)s_w2a;
        for (int i = t; i < 384; i += 256) db[i] = b[i];
        const uint4* c = (const uint4*)(ws + OFF_WDWH);
        uint4* dc = (uint4*)s_wdwh;
        for (int i = t; i < 216; i += 256) dc[i] = c[i];
        const float* f1 = (const float*)(ws + OFF_FQ1);
        const float* f2 = (const float*)(ws + OFF_FQ2);
        for (int i = t; i < 192; i += 256) {
            s_fqA1[i] = f1[i]; s_fqB1[i] = f1[192+i];
            s_fqA2[i] = f2[i]; s_fqB2[i] = f2[192+i];
        }
        const float* b1p = (const float*)(ws + OFF_BN1);
        const float* b2p = (const float*)(ws + OFF_BN2);
        for (int i = t; i < 576; i += 256) { s_bn1[i] = b1p[i]; s_bn2[i] = b2p[i]; }
        const float* b3p = (const float*)(ws + OFF_BN3);
        if (t < 96) s_bn3[t] = b3p[t];
        if (t == 0) {
            s_af1 = (int)((const unsigned*)(ws + OFF_FQ1))[576];
            s_af2 = (int)((const unsigned*)(ws + OFF_FQ2))[576];
        }
    }

    const unsigned* scal = (const unsigned*)(ws + OFF_SCAL);
    const float* wsc = (const float*)(ws + OFF_WSC);
    const unsigned char* xq = ws + OFF_XQ;

    const float sx  = __uint_as_float(scal[0]) + 1e-8f;
    const float s1v = __uint_as_float(scal[1]) + 1e-8f;
    const float s2v = __uint_as_float(scal[2]) + 1e-8f;
    const float C1  = (float)(((double)sx  / 7.0)  * ((double)wsc[0] / 7.0));
    const float C2  = (float)(((double)s1v / 15.0) * ((double)wsc[1] / 7.0));
    const float C3  = (float)(((double)s2v / 15.0) * ((double)wsc[2] / 7.0));

    const int tile = blockIdx.x, n = blockIdx.y;
    const int y0 = (tile >> 3) * 14, x0 = (tile & 7) * 14;
    const int lane = t & 63, wid = t >> 6;
    const int ty = t >> 4, tx = t & 15;
    const bool act = (ty < 14) && (tx < 14);
    const int px = lane & 15, kq = lane >> 4;

    // conv1 B-fragments: group g = 4*wid+i, pixel = g*16 + px, 8 bytes at kq*8
    ull  xb[4];
    bool okb[4];
#pragma unroll
    for (int i = 0; i < 4; ++i) {
        int g = 4*wid + i;
        int bhy = y0 - 1 + g, bwx = x0 - 1 + px;
        bool ok = (bhy >= 0) && (bhy < WID) && (bwx >= 0) && (bwx < WID);
        okb[i] = ok;
        ull v = 0;
        if (ok) v = *(const ull*)(xq + (((size_t)n * HW + bhy * WID + bwx) * 32 + kq * 8));
        xb[i] = v;
    }
    __syncthreads();   // staging complete

    v4i acc2[2][4];
#pragma unroll
    for (int o = 0; o < 2; ++o)
#pragma unroll
        for (int i = 0; i < 4; ++i) { acc2[o][i][0]=0; acc2[o][i][1]=0; acc2[o][i][2]=0; acc2[o][i][3]=0; }

    for (int ph = 0; ph < 12; ++ph) {
        // ---- conv1 MFMA: 16 oc x 64 pixels per wave; j1 -> f16 quads in LDS ----
        ull a1 = s_w1a[ph*64 + lane];
        const int oc0 = ph*16 + kq*4;
        float4 A14 = *(const float4*)&s_fqA1[oc0];
        float4 B14 = *(const float4*)&s_fqB1[oc0];
#pragma unroll
        for (int i = 0; i < 4; ++i) {
            v4i z = {0,0,0,0};
            v4i d = mfma_i8(a1, xb[i], z);
            float4 j1v;
            if (s_af1) {
                j1v.x = okb[i] ? qfast15((float)d[0], A14.x, B14.x) : 0.f;
                j1v.y = okb[i] ? qfast15((float)d[1], A14.y, B14.y) : 0.f;
                j1v.z = okb[i] ? qfast15((float)d[2], A14.z, B14.z) : 0.f;
                j1v.w = okb[i] ? qfast15((float)d[3], A14.w, B14.w) : 0.f;
            } else {
                float jj[4];
#pragma unroll
                for (int r = 0; r < 4; ++r) {
                    int oc = oc0 + r;
                    float h1 = bnq((float)d[r], C1, s_bn1[192+oc], s_bn1[oc], s_bn1[384+oc]);
                    jj[r] = okb[i] ? qexact15(h1, s1v) : 0.f;
                }
                j1v.x = jj[0]; j1v.y = jj[1]; j1v.z = jj[2]; j1v.w = jj[3];
            }
            jlh[kq][PADP((4*wid + i)*16 + px)] =
                make_uint2(h2u(pkrtz(j1v.x, j1v.y)), h2u(pkrtz(j1v.z, j1v.w)));
        }
        __syncthreads();   // A: jlh ready

        // ---- dw on packed f16 (exact for these integer ranges) + j2 pack ----
        unsigned pw[4] = {0u, 0u, 0u, 0u};
        if (act) {
#pragma unroll
            for (int q = 0; q < 4; ++q) {
                h2 s01 = u2h(0u), s23 = u2h(0u);
                const int qg = ph*4 + q;
#pragma unroll
                for (int dy = 0; dy < 3; ++dy)
#pragma unroll
                    for (int dx = 0; dx < 3; ++dx) {
                        uint2 jv = jlh[q][PADP((ty+dy)*16 + tx+dx) - ((ty+dy)*16 + tx+dx == 0 ? 0 : 0)];
                        // PADP applied to the same linear index used by the writer
                        jv = jlh[q][PADP((ty+dy)*16 + (tx+dx))];
                        uint2 wv = s_wdwh[qg*9 + dy*3 + dx];
                        s01 += u2h(jv.x) * u2h(wv.x);
                        s23 += u2h(jv.y) * u2h(wv.y);
                    }
                float f0 = (float)s01[0], f1 = (float)s01[1];
                float f2 = (float)s23[0], f3 = (float)s23[1];
                const int oc2 = ph*16 + q*4;
                float j2a, j2b, j2c, j2d;
                if (s_af2) {
                    float4 A24 = *(const float4*)&s_fqA2[oc2];
                    float4 B24 = *(const float4*)&s_fqB2[oc2];
                    j2a = qfast15(f0, A24.x, B24.x);
                    j2b = qfast15(f1, A24.y, B24.y);
                    j2c = qfast15(f2, A24.z, B24.z);
                    j2d = qfast15(f3, A24.w, B24.w);
                } else {
                    j2a = qexact15(bnq(f0, C2, s_bn2[192+oc2],   s_bn2[oc2],   s_bn2[384+oc2]),   s2v);
                    j2b = qexact15(bnq(f1, C2, s_bn2[192+oc2+1], s_bn2[oc2+1], s_bn2[384+oc2+1]), s2v);
                    j2c = qexact15(bnq(f2, C2, s_bn2[192+oc2+2], s_bn2[oc2+2], s_bn2[384+oc2+2]), s2v);
                    j2d = qexact15(bnq(f3, C2, s_bn2[192+oc2+3], s_bn2[oc2+3], s_bn2[384+oc2+3]), s2v);
                }
                pw[q] = ((unsigned)(int)j2a) | ((unsigned)(int)j2b << 8) |
                        ((unsigned)(int)j2c << 16) | ((unsigned)(int)j2d << 24);
            }
        }
#pragma unroll
        for (int q = 0; q < 4; ++q) j2buf[t][(ph & 1) * 4 + q] = pw[q];
        __syncthreads();   // B: dw reads done, j2buf slot written

        // ---- conv2 MFMA for the completed 32-channel chunk (odd phases) ----
        // next phase's barrier A orders these reads before the next j2buf writes
        if (ph & 1) {
            const int chunk = ph >> 1;
#pragma unroll
            for (int oct = 0; oct < 2; ++oct) {
                ull a2 = s_w2a[(oct*6 + chunk)*64 + lane];
#pragma unroll
                for (int i = 0; i < 4; ++i) {
                    int row = (4*wid + i)*16 + px;
                    unsigned w0 = j2buf[row][kq*2], w1 = j2buf[row][kq*2 + 1];
                    ull b2 = (ull)w0 | ((ull)w1 << 32);
                    acc2[oct][i] = mfma_i8(a2, b2, acc2[oct][i]);
                }
            }
        }
    }

    // ---- bn3 + store h3 + max|h3| ----
    float mx = 0.f;
#pragma unroll
    for (int oct = 0; oct < 2; ++oct)
#pragma unroll
        for (int i = 0; i < 4; ++i) {
            int g = 4*wid + i;
            if (g < 14 && px < 14) {
                int gy = y0 + g, gx = x0 + px;
#pragma unroll
                for (int r = 0; r < 4; ++r) {
                    int oc = oct*16 + kq*4 + r;
                    float y = __fmul_rn((float)acc2[oct][i][r], C3);
                    float h = __fadd_rn(__fmul_rn(__fsub_rn(y, s_bn3[32+oc]), s_bn3[oc]), s_bn3[64+oc]);
                    h3[((size_t)n * COUT + oc) * HW + gy * WID + gx] = h;
                    mx = fmaxf(mx, fabsf(h));
                }
            }
        }
    float r = bmax256(mx, red);
    if (t == 0) atomicMax((unsigned*)(ws + OFF_SCAL) + 3, __float_as_uint(r));
}

// in-place on d_out: out = x + actq_signed(h3)
__global__ __launch_bounds__(256) void kout(const float4* __restrict__ x4,
                                            float4* __restrict__ io4,
                                            const unsigned char* __restrict__ ws)
{
    const unsigned* scal = (const unsigned*)(ws + OFF_SCAL);
    const float s3v = __uint_as_float(scal[3]) + 1e-8f;

    for (size_t i = (size_t)blockIdx.x*256 + threadIdx.x; i < NX/4; i += (size_t)gridDim.x*256) {
        float4 h = io4[i], xv = x4[i], o;
        float* hp = &h.x; float* xp = &xv.x; float* op = &o.x;
#pragma unroll
        for (int k = 0; k < 4; ++k) {
            float tq = fminf(fmaxf(hp[k] / s3v, -1.f), 1.f);
            float kq = rintf(__fmul_rn(tq, 7.f));
            float q  = __fmul_rn(kq / 7.f, s3v);
            op[k] = __fadd_rn(xp[k], q);
        }
        io4[i] = o;
    }
}

extern "C" void kernel_launch(void* const* d_in, const int* in_sizes, int n_in,
                              void* d_out, int out_size, void* d_ws, size_t ws_size,
                              hipStream_t stream)
{
    const float* x   = (const float*)d_in[0];
    const float* w1  = (const float*)d_in[1];
    const float* g1  = (const float*)d_in[2];
    const float* b1  = (const float*)d_in[3];
    const float* m1  = (const float*)d_in[4];
    const float* v1  = (const float*)d_in[5];
    const float* wdw = (const float*)d_in[6];
    const float* g2  = (const float*)d_in[7];
    const float* b2  = (const float*)d_in[8];
    const float* m2  = (const float*)d_in[9];
    const float* v2  = (const float*)d_in[10];
    const float* w2  = (const float*)d_in[11];
    const float* g3  = (const float*)d_in[12];
    const float* b3  = (const float*)d_in[13];
    const float* m3  = (const float*)d_in[14];
    const float* v3  = (const float*)d_in[15];
    unsigned char* ws = (unsigned char*)d_ws;

    hipLaunchKernelGGL(kprepx, dim3(2048), dim3(256), 0, stream, (const float4*)x,
                       w1, wdw, w2, g1, b1, m1, v1, g2, b2, m2, v2, g3, b3, m3, v3, ws);
    hipLaunchKernelGGL(kmax1q, dim3(NPIX/256), dim3(256), 0, stream, x, ws);
    hipLaunchKernelGGL(kcoef, dim3(CMID), dim3(64), 0, stream, ws, 1);
    hipLaunchKernelGGL(kmax2, dim3(64, NB), dim3(256), 0, stream, ws);
    hipLaunchKernelGGL(kcoef, dim3(CMID), dim3(64), 0, stream, ws, 2);
    hipLaunchKernelGGL(kconv2, dim3(64, NB), dim3(256), 0, stream, ws, (float*)d_out);
    hipLaunchKernelGGL(kout, dim3(2048), dim3(256), 0, stream,
                       (const float4*)x, (float4*)d_out, ws);
}

// Round 9
// 228.947 us; speedup vs baseline: 4.2620x; 1.1233x over previous
//
#include <hip/hip_runtime.h>

// InvertedResidualQ on MI355X. Exact-integer quantized-conv formulation.
// R9 = R8 + kconv2 LDS diet (43->36 KB -> 4 blocks/CU): bn1/bn2 fallback
// tables moved to global reads (fast path never touches them), reduction
// buffer overlaid on j2buf, launch_bounds(256,4). Numerics unchanged.

#define HW    12544      // 112*112
#define WID   112
#define CIN   32
#define CMID  192
#define COUT  32
#define NB    32
#define NPIX  (NB*HW)        // 401408
#define NX    (NB*CIN*HW)    // 12845056

// workspace layout (bytes)
#define OFF_SCAL   0         // 4 u32: [0]=sx (plain store), 1..3 atomic-max s1,s2,s3
#define OFF_WSC    16        // 3 f32 weight scales
#define OFF_BN1    64        // gi[192], m[192], b[192]
#define OFF_BN2    2368
#define OFF_BN3    4672      // gi[32], m[32], b[32] (384B)
#define OFF_FQ1    5120      // A[192],B[192] f32, flag[192] u32, allfast u32
#define OFF_FQ2    7488
#define OFF_W1P    9856      // 192*8 u32 packed i8 conv1 weights (sdot4 path)
#define OFF_WDW    16000     // 192*9 f32 dw codes (kmax2)
#define OFF_W1A    22912     // 12*64*8B conv1 A-fragments
#define OFF_W2A    29056     // 2*6*64*8B conv2 A-fragments
#define OFF_WDWH   35200     // 48*9 uint2 (4x f16 dw codes per quad-tap)
#define OFF_PMAX   42112     // 2048 f32 per-block |x| partial maxes
#define OFF_XQ     65536     // NPIX*32 i8 packed input codes, [pix][ic]

#define PADP(p) ((p) + ((p) >> 4))   // 16->17 row stride: kills LDS row aliasing

typedef int v4i __attribute__((ext_vector_type(4)));
typedef unsigned long long ull;
typedef _Float16 h2 __attribute__((ext_vector_type(2)));

__device__ __forceinline__ unsigned h2u(h2 v){ union{h2 h; unsigned u;} c; c.h=v; return c.u; }
__device__ __forceinline__ h2 u2h(unsigned u){ union{h2 h; unsigned u;} c; c.u=u; return c.h; }
__device__ __forceinline__ h2 pkrtz(float a, float b){
    auto r = __builtin_amdgcn_cvt_pkrtz(a, b);      // __fp16x2
    union { decltype(r) f; h2 h; } c; c.f = r; return c.h;
}

#if defined(__has_builtin)
#if __has_builtin(__builtin_amdgcn_sdot4)
#define HAVE_SDOT4 1
#endif
#endif

__device__ __forceinline__ int sdot4(unsigned a, unsigned b, int c) {
#ifdef HAVE_SDOT4
    return __builtin_amdgcn_sdot4((int)a, (int)b, c, false);
#else
    c += (int)(signed char)(a & 0xff)        * (int)(signed char)(b & 0xff);
    c += (int)(signed char)((a >> 8) & 0xff) * (int)(signed char)((b >> 8) & 0xff);
    c += (int)(signed char)((a >> 16) & 0xff)* (int)(signed char)((b >> 16) & 0xff);
    c += (int)(signed char)(a >> 24)         * (int)(signed char)(b >> 24);
    return c;
#endif
}

__device__ __forceinline__ v4i mfma_i8(ull a, ull b, v4i c) {
    return __builtin_amdgcn_mfma_i32_16x16x32_i8((long)a, (long)b, c, 0, 0, 0);
}

__device__ __forceinline__ float bmax256(float v, float* red) {
    const int t = threadIdx.x;
    red[t] = v; __syncthreads();
    for (int s = 128; s; s >>= 1) {
        if (t < s) red[t] = fmaxf(red[t], red[t + s]);
        __syncthreads();
    }
    float r = red[0]; __syncthreads();
    return r;
}

__device__ __forceinline__ float qcode(float x, float s, float n, float lo) {
    float t = x / s;
    t = fminf(fmaxf(t, lo), 1.0f);
    return rintf(__fmul_rn(t, n));
}

__device__ __forceinline__ float bnq(float d, float C, float m, float g, float b) {
    float y = __fmul_rn(d, C);
    float h = __fadd_rn(__fmul_rn(__fsub_rn(y, m), g), b);
    return fminf(fmaxf(h, 0.f), 6.f);
}

__device__ __forceinline__ float qexact15(float h, float s) {
    return rintf(__fmul_rn(fminf(h / s, 1.f), 15.f));
}
__device__ __forceinline__ float qfast15(float df, float A, float B) {
    float t = fmaf(df, A, B);
    return rintf(fminf(fmaxf(t, 0.f), 15.f));
}

// merged prep (block 0) + |x| partial max (all blocks -> pmax[block])
__global__ __launch_bounds__(256) void kprepx(
    const float4* __restrict__ x4,
    const float* __restrict__ w1, const float* __restrict__ wdw, const float* __restrict__ w2,
    const float* __restrict__ g1, const float* __restrict__ b1, const float* __restrict__ m1, const float* __restrict__ v1,
    const float* __restrict__ g2, const float* __restrict__ b2, const float* __restrict__ m2, const float* __restrict__ v2,
    const float* __restrict__ g3, const float* __restrict__ b3, const float* __restrict__ m3, const float* __restrict__ v3,
    unsigned char* __restrict__ ws)
{
    __shared__ float red[256];
    const int t = threadIdx.x;

    if (blockIdx.x == 0) {
        unsigned* scal = (unsigned*)(ws + OFF_SCAL);
        float* wsc  = (float*)(ws + OFF_WSC);
        float* bn1  = (float*)(ws + OFF_BN1);
        float* bn2  = (float*)(ws + OFF_BN2);
        float* bn3  = (float*)(ws + OFF_BN3);
        unsigned* w1p = (unsigned*)(ws + OFF_W1P);
        float*  wdwf  = (float*)(ws + OFF_WDW);

        if (t < 4) scal[t] = 0u;
        if (t == 0) { ((unsigned*)(ws+OFF_FQ1))[576] = 1u; ((unsigned*)(ws+OFF_FQ2))[576] = 1u; }

        float m;
        m = 0.f; for (int i = t; i < CMID*CIN; i += 256) m = fmaxf(m, fabsf(w1[i]));
        float sw1 = bmax256(m, red) + 1e-8f;
        m = 0.f; for (int i = t; i < CMID*9; i += 256) m = fmaxf(m, fabsf(wdw[i]));
        float swd = bmax256(m, red) + 1e-8f;
        m = 0.f; for (int i = t; i < COUT*CMID; i += 256) m = fmaxf(m, fabsf(w2[i]));
        float sw2 = bmax256(m, red) + 1e-8f;
        if (t == 0) { wsc[0] = sw1; wsc[1] = swd; wsc[2] = sw2; }

        // packed i8 conv1 weights (sdot4 path, kmax1q/kmax2)
        for (int i = t; i < CMID*8; i += 256) {
            int oc = i >> 3, j = i & 7;
            unsigned wword = 0;
#pragma unroll
            for (int k = 0; k < 4; ++k) {
                int code = (int)qcode(w1[oc*CIN + 4*j + k], sw1, 7.f, -1.f);
                wword |= ((unsigned)code & 0xffu) << (8*k);
            }
            w1p[i] = wword;
        }
        for (int i = t; i < CMID*9; i += 256) wdwf[i] = qcode(wdw[i], swd, 7.f, -1.f);

        // conv1 A-fragments: [octile][lane] 8B, oc = octile*16+(l&15), ic = (l>>4)*8+e
        for (int i = t; i < 12*64; i += 256) {
            int octile = i >> 6, l = i & 63;
            int oc = octile*16 + (l & 15), icb = (l >> 4) * 8;
            unsigned lo = 0, hi = 0;
#pragma unroll
            for (int k = 0; k < 4; ++k) {
                lo |= ((unsigned)(int)qcode(w1[oc*CIN + icb + k],     sw1, 7.f, -1.f) & 0xffu) << (8*k);
                hi |= ((unsigned)(int)qcode(w1[oc*CIN + icb + 4 + k], sw1, 7.f, -1.f) & 0xffu) << (8*k);
            }
            ((unsigned*)(ws + OFF_W1A))[i*2]   = lo;
            ((unsigned*)(ws + OFF_W1A))[i*2+1] = hi;
        }
        // conv2 A-fragments: [oct][chunk][lane] 8B, oc = oct*16+(l&15), ch = chunk*32+(l>>4)*8+e
        for (int i = t; i < 2*6*64; i += 256) {
            int oct = i / 384, rem = i % 384, chunk = rem >> 6, l = rem & 63;
            int oc = oct*16 + (l & 15), cb = chunk*32 + (l >> 4) * 8;
            unsigned lo = 0, hi = 0;
#pragma unroll
            for (int k = 0; k < 4; ++k) {
                lo |= ((unsigned)(int)qcode(w2[oc*CMID + cb + k],     sw2, 7.f, -1.f) & 0xffu) << (8*k);
                hi |= ((unsigned)(int)qcode(w2[oc*CMID + cb + 4 + k], sw2, 7.f, -1.f) & 0xffu) << (8*k);
            }
            ((unsigned*)(ws + OFF_W2A))[i*2]   = lo;
            ((unsigned*)(ws + OFF_W2A))[i*2+1] = hi;
        }
        // dw weights as packed f16 quad pairs: [qg][tap] -> 2x half2 (exact ints)
        for (int i = t; i < 48*9; i += 256) {
            int qg = i / 9, tap = i % 9;
            float c0 = qcode(wdw[(qg*4+0)*9 + tap], swd, 7.f, -1.f);
            float c1 = qcode(wdw[(qg*4+1)*9 + tap], swd, 7.f, -1.f);
            float c2 = qcode(wdw[(qg*4+2)*9 + tap], swd, 7.f, -1.f);
            float c3 = qcode(wdw[(qg*4+3)*9 + tap], swd, 7.f, -1.f);
            ((uint2*)(ws + OFF_WDWH))[i] = make_uint2(h2u(pkrtz(c0, c1)), h2u(pkrtz(c2, c3)));
        }

        for (int c = t; c < CMID; c += 256) {
            float vv1 = v1[c] + 1e-5f;
            bn1[c] = __fmul_rn(g1[c], (float)(1.0 / sqrt((double)vv1)));
            bn1[192+c] = m1[c]; bn1[384+c] = b1[c];
            float vv2 = v2[c] + 1e-5f;
            bn2[c] = __fmul_rn(g2[c], (float)(1.0 / sqrt((double)vv2)));
            bn2[192+c] = m2[c]; bn2[384+c] = b2[c];
        }
        for (int c = t; c < COUT; c += 256) {
            float vv3 = v3[c] + 1e-5f;
            bn3[c] = __fmul_rn(g3[c], (float)(1.0 / sqrt((double)vv3)));
            bn3[32+c] = m3[c]; bn3[64+c] = b3[c];
        }
    }

    // |x| partial max -> pmax[blockIdx.x] (plain store, no reset race)
    float m = 0.f;
    for (size_t i = (size_t)blockIdx.x*256 + t; i < NX/4; i += (size_t)gridDim.x*256) {
        float4 v = x4[i];
        m = fmaxf(m, fmaxf(fmaxf(fabsf(v.x), fabsf(v.y)), fmaxf(fabsf(v.z), fabsf(v.w))));
    }
    float r = bmax256(m, red);
    if (t == 0) ((float*)(ws + OFF_PMAX))[blockIdx.x] = r;
}

// quantize x -> xq packed codes; conv1 max-scan (sdot4) with wave ANY-exit
__global__ __launch_bounds__(256) void kmax1q(const float* __restrict__ x,
                                              unsigned char* __restrict__ ws)
{
    __shared__ unsigned s_w1p[CMID*8];
    __shared__ float s_bn1[576];
    __shared__ float red[256];
    const int t = threadIdx.x;

    {
        const uint4* src = (const uint4*)(ws + OFF_W1P);
        uint4* dst = (uint4*)s_w1p;
        for (int i = t; i < CMID*8/4; i += 256) dst[i] = src[i];
        const float* b = (const float*)(ws + OFF_BN1);
        for (int i = t; i < 576; i += 256) s_bn1[i] = b[i];
    }

    const float* wsc = (const float*)(ws + OFF_WSC);
    unsigned char* xq = ws + OFF_XQ;

    // self-reduce per-block partials -> sx (identical in every block)
    float pm = 0.f;
    const float* pmax = (const float*)(ws + OFF_PMAX);
    for (int i = t; i < 2048; i += 256) pm = fmaxf(pm, pmax[i]);
    float sxr = bmax256(pm, red);
    if (blockIdx.x == 0 && t == 0) ((unsigned*)(ws + OFF_SCAL))[0] = __float_as_uint(sxr);
    const float sx = sxr + 1e-8f;
    const float C1 = (float)(((double)sx / 7.0) * ((double)wsc[0] / 7.0));

    const int p = blockIdx.x * 256 + t;
    const int n = p / HW, pi = p % HW;
    const float* xp = x + (size_t)n * CIN * HW + pi;

    float kx[CIN];
#pragma unroll
    for (int ic = 0; ic < CIN; ++ic) {
        float v = xp[(size_t)ic * HW] / sx;
        v = fminf(fmaxf(v, -1.f), 1.f);
        kx[ic] = rintf(__fmul_rn(v, 7.f));
    }

    unsigned wb[8];
#pragma unroll
    for (int j = 0; j < 8; ++j) {
        unsigned b0 = (unsigned)(int)kx[4*j]     & 0xffu;
        unsigned b1 = (unsigned)(int)kx[4*j + 1] & 0xffu;
        unsigned b2 = (unsigned)(int)kx[4*j + 2] & 0xffu;
        unsigned b3 = (unsigned)(int)kx[4*j + 3] & 0xffu;
        wb[j] = b0 | (b1 << 8) | (b2 << 16) | (b3 << 24);
    }
    uint4* q4 = (uint4*)(xq + (size_t)p * 32);
    q4[0] = make_uint4(wb[0], wb[1], wb[2], wb[3]);
    q4[1] = make_uint4(wb[4], wb[5], wb[6], wb[7]);

    __syncthreads();

    float mx = 0.f;
    for (int oc = 0; oc < CMID; ++oc) {
        int d = 0;
#pragma unroll
        for (int j = 0; j < 8; ++j) d = sdot4(wb[j], s_w1p[oc*8 + j], d);
        float h = bnq((float)d, C1, s_bn1[192+oc], s_bn1[oc], s_bn1[384+oc]);
        mx = fmaxf(mx, h);
        if (__any(mx >= 6.0f)) break;    // any lane capped -> wave max settled (=6)
    }
    float r = bmax256(mx, red);
    if (t == 0) atomicMax((unsigned*)(ws + OFF_SCAL) + 1, __float_as_uint(r));
}

// per-channel fast-quant coefficients + EXHAUSTIVE verification
__global__ __launch_bounds__(64) void kcoef(unsigned char* __restrict__ ws, int stage)
{
    const unsigned* scal = (const unsigned*)(ws + OFF_SCAL);
    const float* wsc = (const float*)(ws + OFF_WSC);
    const int c = blockIdx.x, lane = threadIdx.x;
    const float* bn = (const float*)(ws + (stage == 1 ? OFF_BN1 : OFF_BN2));
    float* fq = (float*)(ws + (stage == 1 ? OFF_FQ1 : OFF_FQ2));

    float C, s; int R;
    if (stage == 1) {
        float sx = __uint_as_float(scal[0]) + 1e-8f;
        C = (float)(((double)sx / 7.0) * ((double)wsc[0] / 7.0));
        s = __uint_as_float(scal[1]) + 1e-8f;
        R = 1568;
    } else {
        float s1 = __uint_as_float(scal[1]) + 1e-8f;
        C = (float)(((double)s1 / 15.0) * ((double)wsc[1] / 7.0));
        s = __uint_as_float(scal[2]) + 1e-8f;
        R = 945;
    }
    const float gi = bn[c], mm = bn[192+c], bb = bn[384+c];
    const float A = (float)((double)C * (double)gi * 15.0 / (double)s);
    const float B = (float)(((double)bb - (double)mm * (double)gi) * 15.0 / (double)s);

    bool bad = false;
    for (int d = -R + lane; d <= R; d += 64) {
        float df = (float)d;
        float je = qexact15(bnq(df, C, mm, gi, bb), s);
        float jf = qfast15(df, A, B);
        if (je != jf) bad = true;
    }
    bool any = __any(bad);
    if (lane == 0) {
        unsigned flagv = any ? 0u : 1u;
        fq[c] = A; fq[192+c] = B;
        ((unsigned*)fq)[384+c] = flagv;
        atomicAnd(((unsigned*)fq) + 576, flagv);
    }
}

// tile 14x14 out, halo 16x16 = 256 = blockDim; conv1(sdot4)+dw max(h2) scan
// with block ANY-hit early exit (cap 6). (usually exits after 1 phase)
__global__ __launch_bounds__(256) void kmax2(unsigned char* __restrict__ ws)
{
    __shared__ unsigned s_w1p[CMID*8];
    __shared__ float s_wdw[CMID*9];
    __shared__ float s_bn2[576];
    __shared__ unsigned s_fq1[576];
    __shared__ float jl[8][256];
    __shared__ float red[256];
    __shared__ unsigned s_flag;
    const int t = threadIdx.x;

    {
        const uint4* sp = (const uint4*)(ws + OFF_W1P);
        uint4* dp = (uint4*)s_w1p;
        for (int i = t; i < CMID*8/4; i += 256) dp[i] = sp[i];
        const float* wp = (const float*)(ws + OFF_WDW);
        for (int i = t; i < CMID*9; i += 256) s_wdw[i] = wp[i];
        const float* b2p = (const float*)(ws + OFF_BN2);
        for (int i = t; i < 576; i += 256) s_bn2[i] = b2p[i];
        const unsigned* fp = (const unsigned*)(ws + OFF_FQ1);
        for (int i = t; i < 576; i += 256) s_fq1[i] = fp[i];
        if (t == 0) s_flag = 0u;
    }

    const unsigned* scal = (const unsigned*)(ws + OFF_SCAL);
    const float* wsc = (const float*)(ws + OFF_WSC);
    const float* gbn1 = (const float*)(ws + OFF_BN1);
    const unsigned char* xq = ws + OFF_XQ;

    const float sx  = __uint_as_float(scal[0]) + 1e-8f;
    const float s1v = __uint_as_float(scal[1]) + 1e-8f;
    const float C1  = (float)(((double)sx  / 7.0)  * ((double)wsc[0] / 7.0));
    const float C2  = (float)(((double)s1v / 15.0) * ((double)wsc[1] / 7.0));

    const int tile = blockIdx.x, n = blockIdx.y;
    const int ty = t >> 4, tx = t & 15;
    const int hy = (tile >> 3) * 14 - 1 + ty;
    const int wx = (tile & 7)  * 14 - 1 + tx;
    const bool inb = (hy >= 0 && hy < WID && wx >= 0 && wx < WID);
    const bool act = (ty < 14) && (tx < 14);

    unsigned wb[8];
    if (inb) {
        const uint4* q4 = (const uint4*)(xq + ((size_t)n * HW + hy * WID + wx) * 32);
        uint4 a = q4[0], b4 = q4[1];
        wb[0]=a.x; wb[1]=a.y; wb[2]=a.z; wb[3]=a.w;
        wb[4]=b4.x; wb[5]=b4.y; wb[6]=b4.z; wb[7]=b4.w;
    } else {
#pragma unroll
        for (int j = 0; j < 8; ++j) wb[j] = 0u;
    }
    __syncthreads();

    float mx = 0.f;
    for (int ph = 0; ph < CMID/8; ++ph) {
#pragma unroll
        for (int k = 0; k < 8; ++k) {
            const int c = ph*8 + k;
            int d1 = 0;
#pragma unroll
            for (int j = 0; j < 8; ++j) d1 = sdot4(wb[j], s_w1p[c*8 + j], d1);
            float j1 = 0.f;
            if (inb) {
                float d1f = (float)d1;
                if (s_fq1[384+c]) {
                    j1 = qfast15(d1f, __uint_as_float(s_fq1[c]), __uint_as_float(s_fq1[192+c]));
                } else {
                    float h1 = bnq(d1f, C1, gbn1[192+c], gbn1[c], gbn1[384+c]);
                    j1 = qexact15(h1, s1v);
                }
            }
            jl[k][t] = j1;
        }
        __syncthreads();
        if (act) {
#pragma unroll
            for (int k = 0; k < 8; ++k) {
                const int c = ph*8 + k;
                const float* wd = s_wdw + c * 9;
                float d2 = 0.f;
#pragma unroll
                for (int dy = 0; dy < 3; ++dy)
#pragma unroll
                    for (int dx = 0; dx < 3; ++dx)
                        d2 = fmaf(jl[k][(ty+dy)*16 + tx+dx], wd[dy*3+dx], d2);
                float h2 = bnq(d2, C2, s_bn2[192+c], s_bn2[c], s_bn2[384+c]);
                mx = fmaxf(mx, h2);
            }
        }
        if (mx >= 6.0f) s_flag = 1u;
        __syncthreads();
        if (s_flag) break;
    }
    float r = bmax256(mx, red);
    if (t == 0) atomicMax((unsigned*)(ws + OFF_SCAL) + 2, __float_as_uint(r));
}

// full chain with MFMA: conv1 MFMA -> j1 (f16 quads, padded LDS) -> dw (pk f16)
// -> j2 bytes (9-word rows) -> conv2 MFMA. LDS-dieted for 4 blocks/CU.
__global__ __launch_bounds__(256, 4) void kconv2(unsigned char* __restrict__ ws,
                                                 float* __restrict__ h3)
{
    __shared__ ull   s_w1a[12*64];
    __shared__ ull   s_w2a[2*6*64];
    __shared__ uint2 s_wdwh[48*9];
    __shared__ float s_fqA1[192], s_fqB1[192], s_fqA2[192], s_fqB2[192];
    __shared__ float s_bn3[96];
    __shared__ uint2 jlh[4][272];           // [kq][padded pixel] 4x f16 channels
    __shared__ unsigned j2buf[256][9];      // 9-word rows: conflict-free
    __shared__ int s_af1, s_af2;
    const int t = threadIdx.x;

    {
        const uint4* a = (const uint4*)(ws + OFF_W1A);
        uint4* da = (uint4*)s_w1a;
        for (int i = t; i < 384; i += 256) da[i] = a[i];
        const uint4* b = (const uint4*)(ws + OFF_W2A);
        uint4* db = (uint4*)s_w2a;
        for (int i = t; i < 384; i += 256) db[i] = b[i];
        const uint4* c = (const uint4*)(ws + OFF_WDWH);
        uint4* dc = (uint4*)s_wdwh;
        for (int i = t; i < 216; i += 256) dc[i] = c[i];
        const float* f1 = (const float*)(ws + OFF_FQ1);
        const float* f2 = (const float*)(ws + OFF_FQ2);
        for (int i = t; i < 192; i += 256) {
            s_fqA1[i] = f1[i]; s_fqB1[i] = f1[192+i];
            s_fqA2[i] = f2[i]; s_fqB2[i] = f2[192+i];
        }
        const float* b3p = (const float*)(ws + OFF_BN3);
        if (t < 96) s_bn3[t] = b3p[t];
        if (t == 0) {
            s_af1 = (int)((const unsigned*)(ws + OFF_FQ1))[576];
            s_af2 = (int)((const unsigned*)(ws + OFF_FQ2))[576];
        }
    }

    const unsigned* scal = (const unsigned*)(ws + OFF_SCAL);
    const float* wsc = (const float*)(ws + OFF_WSC);
    const float* gbn1 = (const float*)(ws + OFF_BN1);   // fallback only
    const float* gbn2 = (const float*)(ws + OFF_BN2);   // fallback only
    const unsigned char* xq = ws + OFF_XQ;

    const float sx  = __uint_as_float(scal[0]) + 1e-8f;
    const float s1v = __uint_as_float(scal[1]) + 1e-8f;
    const float s2v = __uint_as_float(scal[2]) + 1e-8f;
    const float C1  = (float)(((double)sx  / 7.0)  * ((double)wsc[0] / 7.0));
    const float C2  = (float)(((double)s1v / 15.0) * ((double)wsc[1] / 7.0));
    const float C3  = (float)(((double)s2v / 15.0) * ((double)wsc[2] / 7.0));

    const int tile = blockIdx.x, n = blockIdx.y;
    const int y0 = (tile >> 3) * 14, x0 = (tile & 7) * 14;
    const int lane = t & 63, wid = t >> 6;
    const int ty = t >> 4, tx = t & 15;
    const bool act = (ty < 14) && (tx < 14);
    const int px = lane & 15, kq = lane >> 4;

    // conv1 B-fragments: group g = 4*wid+i, pixel = g*16 + px, 8 bytes at kq*8
    ull  xb[4];
    bool okb[4];
#pragma unroll
    for (int i = 0; i < 4; ++i) {
        int g = 4*wid + i;
        int bhy = y0 - 1 + g, bwx = x0 - 1 + px;
        bool ok = (bhy >= 0) && (bhy < WID) && (bwx >= 0) && (bwx < WID);
        okb[i] = ok;
        ull v = 0;
        if (ok) v = *(const ull*)(xq + (((size_t)n * HW + bhy * WID + bwx) * 32 + kq * 8));
        xb[i] = v;
    }
    __syncthreads();   // staging complete

    v4i acc2[2][4];
#pragma unroll
    for (int o = 0; o < 2; ++o)
#pragma unroll
        for (int i = 0; i < 4; ++i) { acc2[o][i][0]=0; acc2[o][i][1]=0; acc2[o][i][2]=0; acc2[o][i][3]=0; }

    for (int ph = 0; ph < 12; ++ph) {
        // ---- conv1 MFMA: 16 oc x 64 pixels per wave; j1 -> f16 quads in LDS ----
        ull a1 = s_w1a[ph*64 + lane];
        const int oc0 = ph*16 + kq*4;
        float4 A14 = *(const float4*)&s_fqA1[oc0];
        float4 B14 = *(const float4*)&s_fqB1[oc0];
#pragma unroll
        for (int i = 0; i < 4; ++i) {
            v4i z = {0,0,0,0};
            v4i d = mfma_i8(a1, xb[i], z);
            float4 j1v;
            if (s_af1) {
                j1v.x = okb[i] ? qfast15((float)d[0], A14.x, B14.x) : 0.f;
                j1v.y = okb[i] ? qfast15((float)d[1], A14.y, B14.y) : 0.f;
                j1v.z = okb[i] ? qfast15((float)d[2], A14.z, B14.z) : 0.f;
                j1v.w = okb[i] ? qfast15((float)d[3], A14.w, B14.w) : 0.f;
            } else {
                float jj[4];
#pragma unroll
                for (int r = 0; r < 4; ++r) {
                    int oc = oc0 + r;
                    float h1 = bnq((float)d[r], C1, gbn1[192+oc], gbn1[oc], gbn1[384+oc]);
                    jj[r] = okb[i] ? qexact15(h1, s1v) : 0.f;
                }
                j1v.x = jj[0]; j1v.y = jj[1]; j1v.z = jj[2]; j1v.w = jj[3];
            }
            jlh[kq][PADP((4*wid + i)*16 + px)] =
                make_uint2(h2u(pkrtz(j1v.x, j1v.y)), h2u(pkrtz(j1v.z, j1v.w)));
        }
        __syncthreads();   // A: jlh ready

        // ---- dw on packed f16 (exact for these integer ranges) + j2 pack ----
        unsigned pw[4] = {0u, 0u, 0u, 0u};
        if (act) {
#pragma unroll
            for (int q = 0; q < 4; ++q) {
                h2 s01 = u2h(0u), s23 = u2h(0u);
                const int qg = ph*4 + q;
#pragma unroll
                for (int dy = 0; dy < 3; ++dy)
#pragma unroll
                    for (int dx = 0; dx < 3; ++dx) {
                        uint2 jv = jlh[q][PADP((ty+dy)*16 + (tx+dx))];
                        uint2 wv = s_wdwh[qg*9 + dy*3 + dx];
                        s01 += u2h(jv.x) * u2h(wv.x);
                        s23 += u2h(jv.y) * u2h(wv.y);
                    }
                float f0 = (float)s01[0], f1 = (float)s01[1];
                float f2 = (float)s23[0], f3 = (float)s23[1];
                const int oc2 = ph*16 + q*4;
                float j2a, j2b, j2c, j2d;
                if (s_af2) {
                    float4 A24 = *(const float4*)&s_fqA2[oc2];
                    float4 B24 = *(const float4*)&s_fqB2[oc2];
                    j2a = qfast15(f0, A24.x, B24.x);
                    j2b = qfast15(f1, A24.y, B24.y);
                    j2c = qfast15(f2, A24.z, B24.z);
                    j2d = qfast15(f3, A24.w, B24.w);
                } else {
                    j2a = qexact15(bnq(f0, C2, gbn2[192+oc2],   gbn2[oc2],   gbn2[384+oc2]),   s2v);
                    j2b = qexact15(bnq(f1, C2, gbn2[192+oc2+1], gbn2[oc2+1], gbn2[384+oc2+1]), s2v);
                    j2c = qexact15(bnq(f2, C2, gbn2[192+oc2+2], gbn2[oc2+2], gbn2[384+oc2+2]), s2v);
                    j2d = qexact15(bnq(f3, C2, gbn2[192+oc2+3], gbn2[oc2+3], gbn2[384+oc2+3]), s2v);
                }
                pw[q] = ((unsigned)(int)j2a) | ((unsigned)(int)j2b << 8) |
                        ((unsigned)(int)j2c << 16) | ((unsigned)(int)j2d << 24);
            }
        }
#pragma unroll
        for (int q = 0; q < 4; ++q) j2buf[t][(ph & 1) * 4 + q] = pw[q];
        __syncthreads();   // B: dw reads done, j2buf slot written

        // ---- conv2 MFMA for the completed 32-channel chunk (odd phases) ----
        // next phase's barrier A orders these reads before the next j2buf writes
        if (ph & 1) {
            const int chunk = ph >> 1;
#pragma unroll
            for (int oct = 0; oct < 2; ++oct) {
                ull a2 = s_w2a[(oct*6 + chunk)*64 + lane];
#pragma unroll
                for (int i = 0; i < 4; ++i) {
                    int row = (4*wid + i)*16 + px;
                    unsigned w0 = j2buf[row][kq*2], w1 = j2buf[row][kq*2 + 1];
                    ull b2 = (ull)w0 | ((ull)w1 << 32);
                    acc2[oct][i] = mfma_i8(a2, b2, acc2[oct][i]);
                }
            }
        }
    }

    // ---- bn3 + store h3 + max|h3| ----
    float mx = 0.f;
#pragma unroll
    for (int oct = 0; oct < 2; ++oct)
#pragma unroll
        for (int i = 0; i < 4; ++i) {
            int g = 4*wid + i;
            if (g < 14 && px < 14) {
                int gy = y0 + g, gx = x0 + px;
#pragma unroll
                for (int r = 0; r < 4; ++r) {
                    int oc = oct*16 + kq*4 + r;
                    float y = __fmul_rn((float)acc2[oct][i][r], C3);
                    float h = __fadd_rn(__fmul_rn(__fsub_rn(y, s_bn3[32+oc]), s_bn3[oc]), s_bn3[64+oc]);
                    h3[((size_t)n * COUT + oc) * HW + gy * WID + gx] = h;
                    mx = fmaxf(mx, fabsf(h));
                }
            }
        }
    __syncthreads();                       // all j2buf reads done before overlay
    float* red = (float*)&j2buf[0][0];     // reuse j2buf space for reduction
    float r = bmax256(mx, red);
    if (t == 0) atomicMax((unsigned*)(ws + OFF_SCAL) + 3, __float_as_uint(r));
}

// in-place on d_out: out = x + actq_signed(h3)
__global__ __launch_bounds__(256) void kout(const float4* __restrict__ x4,
                                            float4* __restrict__ io4,
                                            const unsigned char* __restrict__ ws)
{
    const unsigned* scal = (const unsigned*)(ws + OFF_SCAL);
    const float s3v = __uint_as_float(scal[3]) + 1e-8f;

    for (size_t i = (size_t)blockIdx.x*256 + threadIdx.x; i < NX/4; i += (size_t)gridDim.x*256) {
        float4 h = io4[i], xv = x4[i], o;
        float* hp = &h.x; float* xp = &xv.x; float* op = &o.x;
#pragma unroll
        for (int k = 0; k < 4; ++k) {
            float tq = fminf(fmaxf(hp[k] / s3v, -1.f), 1.f);
            float kq = rintf(__fmul_rn(tq, 7.f));
            float q  = __fmul_rn(kq / 7.f, s3v);
            op[k] = __fadd_rn(xp[k], q);
        }
        io4[i] = o;
    }
}

extern "C" void kernel_launch(void* const* d_in, const int* in_sizes, int n_in,
                              void* d_out, int out_size, void* d_ws, size_t ws_size,
                              hipStream_t stream)
{
    const float* x   = (const float*)d_in[0];
    const float* w1  = (const float*)d_in[1];
    const float* g1  = (const float*)d_in[2];
    const float* b1  = (const float*)d_in[3];
    const float* m1  = (const float*)d_in[4];
    const float* v1  = (const float*)d_in[5];
    const float* wdw = (const float*)d_in[6];
    const float* g2  = (const float*)d_in[7];
    const float* b2  = (const float*)d_in[8];
    const float* m2  = (const float*)d_in[9];
    const float* v2  = (const float*)d_in[10];
    const float* w2  = (const float*)d_in[11];
    const float* g3  = (const float*)d_in[12];
    const float* b3  = (const float*)d_in[13];
    const float* m3  = (const float*)d_in[14];
    const float* v3  = (const float*)d_in[15];
    unsigned char* ws = (unsigned char*)d_ws;

    hipLaunchKernelGGL(kprepx, dim3(2048), dim3(256), 0, stream, (const float4*)x,
                       w1, wdw, w2, g1, b1, m1, v1, g2, b2, m2, v2, g3, b3, m3, v3, ws);
    hipLaunchKernelGGL(kmax1q, dim3(NPIX/256), dim3(256), 0, stream, x, ws);
    hipLaunchKernelGGL(kcoef, dim3(CMID), dim3(64), 0, stream, ws, 1);
    hipLaunchKernelGGL(kmax2, dim3(64, NB), dim3(256), 0, stream, ws);
    hipLaunchKernelGGL(kcoef, dim3(CMID), dim3(64), 0, stream, ws, 2);
    hipLaunchKernelGGL(kconv2, dim3(64, NB), dim3(256), 0, stream, ws, (float*)d_out);
    hipLaunchKernelGGL(kout, dim3(2048), dim3(256), 0, stream,
                       (const float4*)x, (float4*)d_out, ws);
}